// Round 11
// baseline (168.372 us; speedup 1.0000x reference)
//
#include <hip/hip_runtime.h>

#define Bn 256
#define Sn 1024
#define Tn 64
#define NCH 16
#define BURN 64
#define SLAB 4
#define CROW 72             // fb kernel: conv bf16 row stride in shorts
#define MROW 129
#define LN2 0.69314718055994531f
#define L7LN2 4.8520302639196169f   // 7*ln2 (lambda = 2^-7 folded into exp)

typedef __attribute__((ext_vector_type(8))) short short8;
typedef __attribute__((ext_vector_type(4))) float f32x4;

__device__ __forceinline__ unsigned short f2bf_rne(float f) {
  unsigned u = __float_as_uint(f);
  u = (u + 0x7fffu + ((u >> 16) & 1u)) >> 16;
  return (unsigned short)u;
}
__device__ __forceinline__ unsigned pk2(float hi, float lo) {
  return __builtin_amdgcn_perm(__float_as_uint(hi), __float_as_uint(lo), 0x07060302);
}
__device__ __forceinline__ unsigned pke(float a, float b) {  // exp+pack 2 bf16
  return (unsigned)f2bf_rne(__expf(a - L7LN2)) |
         ((unsigned)f2bf_rne(__expf(b - L7LN2)) << 16);
}
__device__ __forceinline__ short8 cat4(uint2 a, uint2 b) {
  union { unsigned u[4]; short8 s; } x;
  x.u[0] = a.x; x.u[1] = a.y; x.u[2] = b.x; x.u[3] = b.y;
  return x.s;
}
__device__ __forceinline__ void gl_lds16(const void* src, void* dst) {
  __builtin_amdgcn_global_load_lds(
      (const __attribute__((address_space(1))) void*)src,
      (__attribute__((address_space(3))) void*)dst, 16, 0, 0);
}
__device__ __forceinline__ void gl_lds4(const void* src, void* dst) {
  __builtin_amdgcn_global_load_lds(
      (const __attribute__((address_space(1))) void*)src,
      (__attribute__((address_space(3))) void*)dst, 4, 0, 0);
}

// ======================= R11 kernel 1: streaming prep =======================
// Pure streaming exp+pack (m13-class shape: 4096 blocks, high occupancy).
// em2 cell (b,t) = 128B of bf16, "scan-lane" layout: 16B granule G holds
// the 8 bf16 a scan lane consumes contiguously; G is XOR-swizzled by (b&7)
// for LDS bank spread. pke pairing identical to prior convS -> bit-identical.
__global__ __launch_bounds__(256) void crf_prep(const float* __restrict__ em,
                                                short* __restrict__ em2) {
  int idx = blockIdx.x * 256 + threadIdx.x;   // 4096*256 == Bn*Sn*4 exactly
  if (idx >= Bn * Sn * 4) return;
  const int cell = idx >> 2;                  // (b,t)
  const int j = idx & 3;                      // q-quadrant
  const int b = cell >> 10;                   // Sn = 1024
  const float* src = em + (size_t)cell * 64;
  float4 v0 = *(const float4*)(src + 8 * j);
  float4 v1 = *(const float4*)(src + 8 * j + 4);
  float4 v2 = *(const float4*)(src + 32 + 8 * j);
  float4 v3 = *(const float4*)(src + 32 + 8 * j + 4);
  uint4 O1, O2;
  O1.x = pke(v0.x, v0.y); O1.y = pke(v0.z, v0.w);   // states 8j..8j+3
  O1.z = pke(v1.x, v1.y); O1.w = pke(v1.z, v1.w);   // states 8j+4..8j+7
  O2.x = pke(v2.x, v2.y); O2.y = pke(v2.z, v2.w);   // states 32+8j..+3
  O2.z = pke(v3.x, v3.y); O2.w = pke(v3.z, v3.w);   // states 32+8j+4..+7
  short* dst = em2 + (size_t)cell * 64;
  const int sw = (b & 7) << 3;                // 16B-granule XOR (8 shorts)
  *(uint4*)(dst + ((j * 16) ^ sw)) = O1;      // eu0|eu1 of lane q=j
  *(uint4*)(dst + ((j * 16 + 8) ^ sw)) = O2;  // eu2|eu3 of lane q=j
}

// ======================= R11 kernel 2: bf16 scan ============================
// 256 blocks x 2 waves. wave0: unchanged MFMA scan reading bf16 straight
// from a 4-deep LDS ring (no conversion anywhere). wave1: pure producer —
// 8 gl_lds16 per slab (HALF the bytes of f32 staging), slab r+3 issued at
// round r, counted in-order vmcnt (14/6/0) never drains in steady state.
__global__ __launch_bounds__(128, 1) void crf_scan2(
    const float* __restrict__ em, const int* __restrict__ tags,
    const int* __restrict__ mask, const float* __restrict__ trans,
    const float* __restrict__ startt, const float* __restrict__ endt,
    const short* __restrict__ em2,
    float* __restrict__ wsL, float* __restrict__ wsGold,
    int* __restrict__ wsM, float* __restrict__ wsSE, float* __restrict__ wsA,
    int* __restrict__ cnt, float* __restrict__ out) {
  const int g = blockIdx.x & 15;
  const int c = blockIdx.x >> 4;
  const int Wc = (c == 0) ? 0 : BURN;
  const int Lc = (c == NCH - 1) ? 63 : 64;
  const int TOT = Wc + Lc;
  const int NSLAB = (TOT + SLAB - 1) / SLAB;
  const int t0 = 64 * c + 1;
  const int tstart = t0 - Wc;
  const int tid = threadIdx.x;
  const int wid = tid >> 6;
  const int lane = tid & 63;
  const int m = lane & 15;
  const int q = lane >> 4;
  const int mrow = 8 * (m >> 2) + (m & 3);  // permuted A-row base
  const int swm = (m & 7) << 3;             // matches prep's XOR swizzle
  const int hi = lane >> 3, inner = lane & 7;  // producer lane split

  __shared__ __align__(16) short ring[4][SLAB * 16 * 64];  // 32 KB bf16 em
  __shared__ int maskL[16 * MROW];                         // 8.3 KB
  __shared__ int lastF;
  __shared__ float eend[64];
  __shared__ float rsum[2];

  short8 a00, a01, a10, a11, a20, a21, a30, a31;
  uint2 st0, st1, st2, st3;
  float Slog = 0.f;
  int K = 0, NL = 0;
  const f32x4 zero4 = {0.f, 0.f, 0.f, 0.f};

  auto issue_slab = [&](int s) {   // 2*rem gl_lds16 (8 full / 6 tail)
    if (s >= NSLAB) return;
    short* dstb = ring[s & 3];
    const int rem = min(SLAB, TOT - 4 * s);
    const int Ts = tstart + 4 * s;
    for (int u = 0; u < rem; ++u)
      for (int hf = 0; hf < 2; ++hf)
        gl_lds16(em2 + ((size_t)(16 * g + hf * 8 + hi) * Sn + (Ts + u)) * 64 + inner * 8,
                 dstb + (u * 16 + hf * 8) * 64);
  };

  // ================= prologue =================
  if (wid == 0) {
#define LOADA(tm, kc, dst) { \
    _Pragma("unroll") for (int jj = 0; jj < 8; ++jj) { \
      int kk = kc * 32 + q * 8 + jj; \
      dst[jj] = (short)f2bf_rne(__expf(trans[kk * Tn + (32 * ((tm) >> 1) + 4 * ((tm) & 1) + mrow)])); \
    } }
    LOADA(0, 0, a00) LOADA(0, 1, a01) LOADA(1, 0, a10) LOADA(1, 1, a11)
    LOADA(2, 0, a20) LOADA(2, 1, a21) LOADA(3, 0, a30) LOADA(3, 1, a31)
#undef LOADA
    if (c == 0) {  // exact alpha_0 = exp(startt + em[:,0,:]), permuted slots
#define INIT0(off, ss) { \
      float4 sv = *(const float4*)(startt + (off)); \
      float4 ev = *(const float4*)(em + (size_t)(16 * g + m) * Sn * Tn + (off)); \
      ss.x = (unsigned)f2bf_rne(__expf(sv.x + ev.x)) | \
             ((unsigned)f2bf_rne(__expf(sv.y + ev.y)) << 16); \
      ss.y = (unsigned)f2bf_rne(__expf(sv.z + ev.z)) | \
             ((unsigned)f2bf_rne(__expf(sv.w + ev.w)) << 16); }
      INIT0(8 * q, st0) INIT0(8 * q + 4, st1)
      INIT0(32 + 8 * q, st2) INIT0(36 + 8 * q, st3)
#undef INIT0
    } else {
      st0.x = 0x3F803F80u; st0.y = 0x3F803F80u; st1 = st0; st2 = st0; st3 = st0;
    }
    if (c == NCH - 1 && g == 15) {  // mask repair (wave1 skips this slot)
      int t = tstart + 64 + lane;
      if (t < Sn) maskL[15 * MROW + 64 + lane] = mask[(size_t)255 * Sn + t];
    }
    asm volatile("s_waitcnt vmcnt(0) lgkmcnt(0)" ::: "memory");
  } else {
    // mask staging (gl_lds, oldest in queue)
    for (int mm = 0; mm < 16; ++mm) {
      gl_lds4(mask + (size_t)(16 * g + mm) * Sn + tstart + lane,
              (void*)(maskL + mm * MROW));
      bool special = (c == NCH - 1) && (g == 15) && (mm == 15);  // OOB t=1024
      if (!special)
        gl_lds4(mask + (size_t)(16 * g + mm) * Sn + tstart + 64 + lane,
                (void*)(maskL + mm * MROW + 64));
    }
    // gold partials (plain loads; consumption drains them + older mask)
    {
      const int bm = 16 * g + m;
      const int* tg = tags + (size_t)bm * Sn;
      const int* mkb = mask + (size_t)bm * Sn;
      const float* emb = em + (size_t)bm * Sn * Tn;
      float acc = 0.f;
      int cntg = 0;
      #pragma unroll 4
      for (int i = 0; i < 16; ++i) {
        int t = t0 + q + 4 * i;
        bool ok = t < t0 + Lc;
        int ts = ok ? t : t0;
        int mv = mkb[ts];
        int tp = tg[ts - 1], tc = tg[ts];
        float w = trans[tp * Tn + tc] + emb[(size_t)ts * Tn + tc];
        acc += (ok && mv) ? w : 0.f;
        cntg += ok ? mv : 0;
      }
      acc += __shfl_xor(acc, 16); acc += __shfl_xor(acc, 32);
      cntg += __shfl_xor(cntg, 16); cntg += __shfl_xor(cntg, 32);
      if (q == 0) { wsGold[c * 256 + bm] = acc; wsM[c * 256 + bm] = cntg; }
    }
    asm volatile("s_waitcnt vmcnt(0)" ::: "memory");  // mask+gold done
    issue_slab(0); issue_slab(1); issue_slab(2);
    asm volatile("s_waitcnt vmcnt(16)" ::: "memory"); // slab0 done; 1,2 fly
  }
  __builtin_amdgcn_s_barrier();   // B1: ring[0] + maskL ready
  asm volatile("" ::: "memory");

  // ================= rounds =================
#define UNP(ss, x0, x1, x2, x3) \
  x0 = __uint_as_float(ss.x << 16); x1 = __uint_as_float(ss.x & 0xffff0000u); \
  x2 = __uint_as_float(ss.y << 16); x3 = __uint_as_float(ss.y & 0xffff0000u);

  auto renorm = [&](int ttz) {
    float x00, x01, x02, x03, x10, x11, x12, x13;
    float x20, x21, x22, x23, x30, x31, x32, x33;
    UNP(st0, x00, x01, x02, x03) UNP(st1, x10, x11, x12, x13)
    UNP(st2, x20, x21, x22, x23) UNP(st3, x30, x31, x32, x33)
    float sm = (((x00 + x01) + (x02 + x03)) + ((x10 + x11) + (x12 + x13)))
             + (((x20 + x21) + (x22 + x23)) + ((x30 + x31) + (x32 + x33)));
    sm += __shfl_xor(sm, 16); sm += __shfl_xor(sm, 32);
    if (c != 0 && ttz == BURN) { Slog = __logf(sm); K = 0; NL = 0; }
    int k = 127 - (int)((__float_as_uint(sm) >> 23) & 255u);
    float fk = __uint_as_float((unsigned)(127 + k) << 23);
    x00 *= fk; x01 *= fk; x02 *= fk; x03 *= fk;
    x10 *= fk; x11 *= fk; x12 *= fk; x13 *= fk;
    x20 *= fk; x21 *= fk; x22 *= fk; x23 *= fk;
    x30 *= fk; x31 *= fk; x32 *= fk; x33 *= fk;
    st0.x = pk2(x01, x00); st0.y = pk2(x03, x02);
    st1.x = pk2(x11, x10); st1.y = pk2(x13, x12);
    st2.x = pk2(x21, x20); st2.y = pk2(x23, x22);
    st3.x = pk2(x31, x30); st3.y = pk2(x33, x32);
    K += k;
  };

  auto scan_step = [&](const short* cellb, int tt) {
    uint4 E01 = *(const uint4*)(cellb + ((q * 16) ^ swm));
    uint4 E23 = *(const uint4*)(cellb + ((q * 16 + 8) ^ swm));
    uint2 eu0; eu0.x = E01.x; eu0.y = E01.y;
    uint2 eu1; eu1.x = E01.z; eu1.y = E01.w;
    uint2 eu2; eu2.x = E23.x; eu2.y = E23.y;
    uint2 eu3; eu3.x = E23.z; eu3.y = E23.w;
    int mv = maskL[m * MROW + tt];
    short8 b0 = cat4(st0, st1);
    short8 b1 = cat4(st2, st3);
    f32x4 d0 = __builtin_amdgcn_mfma_f32_16x16x32_bf16(a00, b0, zero4, 0, 0, 0);
    f32x4 d1 = __builtin_amdgcn_mfma_f32_16x16x32_bf16(a10, b0, zero4, 0, 0, 0);
    f32x4 d2 = __builtin_amdgcn_mfma_f32_16x16x32_bf16(a20, b0, zero4, 0, 0, 0);
    f32x4 d3 = __builtin_amdgcn_mfma_f32_16x16x32_bf16(a30, b0, zero4, 0, 0, 0);
    d0 = __builtin_amdgcn_mfma_f32_16x16x32_bf16(a01, b1, d0, 0, 0, 0);
    d1 = __builtin_amdgcn_mfma_f32_16x16x32_bf16(a11, b1, d1, 0, 0, 0);
    d2 = __builtin_amdgcn_mfma_f32_16x16x32_bf16(a21, b1, d2, 0, 0, 0);
    d3 = __builtin_amdgcn_mfma_f32_16x16x32_bf16(a31, b1, d3, 0, 0, 0);
    const bool live = (mv != 0);
#define EPI(dd, eu, ss) { \
    float e0 = __uint_as_float(eu.x << 16); \
    float e1 = __uint_as_float(eu.x & 0xffff0000u); \
    float e2 = __uint_as_float(eu.y << 16); \
    float e3 = __uint_as_float(eu.y & 0xffff0000u); \
    unsigned nx = pk2(dd[1] * e1, dd[0] * e0); \
    unsigned ny = pk2(dd[3] * e3, dd[2] * e2); \
    ss.x = live ? nx : ss.x; \
    ss.y = live ? ny : ss.y; }
    EPI(d0, eu0, st0) EPI(d1, eu1, st1) EPI(d2, eu2, st2) EPI(d3, eu3, st3)
#undef EPI
    NL += (live && tt >= Wc) ? 1 : 0;
  };

  const int RT = (TOT - 4) >> 2;
  for (int r = 0; r < NSLAB; ++r) {
    if (wid == 0) {
      if ((r & 1) == 0) renorm(4 * r);
      const short* rb = ring[r & 3];
      if (r < RT) {
        #pragma unroll
        for (int u = 0; u < SLAB; ++u)
          scan_step(rb + (u * 16 + m) * 64, 4 * r + u);
      } else {
        #pragma unroll
        for (int u = 0; u < SLAB; ++u)
          if (4 * r + u < TOT)
            scan_step(rb + (u * 16 + m) * 64, 4 * r + u);
      }
    } else {
      issue_slab(r + 3);   // into ring[(r+3)&3]; ring[r&3] read this round ✓
      // in-order vmcnt: leave only slabs r+2,r+3 in flight; slab r+1 done.
      if (r + 3 < NSLAB)      asm volatile("s_waitcnt vmcnt(14)" ::: "memory");
      else if (r + 2 < NSLAB) asm volatile("s_waitcnt vmcnt(6)" ::: "memory");
      else                    asm volatile("s_waitcnt vmcnt(0)" ::: "memory");
    }
    __builtin_amdgcn_s_barrier();
    asm volatile("" ::: "memory");
  }

  // ================= per-chunk outputs =================
  if (wid == 0) {
    float x00, x01, x02, x03, x10, x11, x12, x13;
    float x20, x21, x22, x23, x30, x31, x32, x33;
    UNP(st0, x00, x01, x02, x03) UNP(st1, x10, x11, x12, x13)
    UNP(st2, x20, x21, x22, x23) UNP(st3, x30, x31, x32, x33)
    float sm = (((x00 + x01) + (x02 + x03)) + ((x10 + x11) + (x12 + x13)))
             + (((x20 + x21) + (x22 + x23)) + ((x30 + x31) + (x32 + x33)));
    sm += __shfl_xor(sm, 16); sm += __shfl_xor(sm, 32);
    const int bm = 16 * g + m;
    float L = __logf(sm) - Slog + LN2 * (float)(7 * NL - K);
    if (q == 0) wsL[c * 256 + bm] = L;
    if (c == NCH - 1) {
      if (q == 0) wsSE[bm] = __logf(sm);
      wsA[(8 * q + 0) * 256 + bm] = x00;  wsA[(8 * q + 1) * 256 + bm] = x01;
      wsA[(8 * q + 2) * 256 + bm] = x02;  wsA[(8 * q + 3) * 256 + bm] = x03;
      wsA[(8 * q + 4) * 256 + bm] = x10;  wsA[(8 * q + 5) * 256 + bm] = x11;
      wsA[(8 * q + 6) * 256 + bm] = x12;  wsA[(8 * q + 7) * 256 + bm] = x13;
      wsA[(32 + 8 * q + 0) * 256 + bm] = x20; wsA[(32 + 8 * q + 1) * 256 + bm] = x21;
      wsA[(32 + 8 * q + 2) * 256 + bm] = x22; wsA[(32 + 8 * q + 3) * 256 + bm] = x23;
      wsA[(36 + 8 * q + 0) * 256 + bm] = x30; wsA[(36 + 8 * q + 1) * 256 + bm] = x31;
      wsA[(36 + 8 * q + 2) * 256 + bm] = x32; wsA[(36 + 8 * q + 3) * 256 + bm] = x33;
    }
  }
#undef UNP

  // ================= fused finale (last block) =================
  __threadfence();
  __syncthreads();
  if (tid == 0) lastF = (atomicAdd(cnt, 1) == 255) ? 1 : 0;
  __syncthreads();
  if (lastF) {
    __threadfence();
    if (tid < 64) eend[tid] = __expf(endt[tid]);
    __syncthreads();
    float vsum = 0.f;
    for (int bb = tid; bb < Bn; bb += 128) {
      float sumL = 0.f, gold = 0.f;
      int msum = 0;
      #pragma unroll
      for (int cc = 0; cc < NCH; ++cc) {
        sumL += wsL[cc * 256 + bb];
        gold += wsGold[cc * 256 + bb];
        msum += wsM[cc * 256 + bb];
      }
      msum += mask[(size_t)bb * Sn];
      float se = 0.f;
      for (int jj = 0; jj < Tn; ++jj) se += wsA[jj * 256 + bb] * eend[jj];
      float logZ = sumL + __logf(se) - wsSE[bb];
      int tg0 = tags[(size_t)bb * Sn];
      int lastTag = tags[(size_t)bb * Sn + (msum - 1)];
      gold += startt[tg0] + em[(size_t)bb * Sn * Tn + tg0] + endt[lastTag];
      vsum += logZ - gold;
    }
    #pragma unroll
    for (int o = 32; o > 0; o >>= 1) vsum += __shfl_xor(vsum, o, 64);
    if (lane == 0) rsum[wid] = vsum;
    __syncthreads();
    if (tid == 0) out[0] = (rsum[0] + rsum[1]) * (1.0f / Bn);
  }
}

// =============== fallback: R8 kernel verbatim (ws too small) ===============
__global__ __launch_bounds__(256, 1) void crf_scan_fb(
    const float* __restrict__ em, const int* __restrict__ tags,
    const int* __restrict__ mask, const float* __restrict__ trans,
    const float* __restrict__ startt, const float* __restrict__ endt,
    float* __restrict__ wsL, float* __restrict__ wsGold,
    int* __restrict__ wsM, float* __restrict__ wsSE, float* __restrict__ wsA,
    int* __restrict__ cnt, float* __restrict__ out) {
  const int g = blockIdx.x & 15;
  const int c = blockIdx.x >> 4;
  const int Wc = (c == 0) ? 0 : BURN;
  const int Lc = (c == NCH - 1) ? 63 : 64;
  const int TOT = Wc + Lc;
  const int NSLAB = (TOT + SLAB - 1) / SLAB;
  const int t0 = 64 * c + 1;
  const int tstart = t0 - Wc;
  const int tid = threadIdx.x;
  const int wid = tid >> 6;
  const int lane = tid & 63;
  const int m = lane & 15;
  const int q = lane >> 4;
  const int mrow = 8 * (m >> 2) + (m & 3);

  __shared__ __align__(16) short convS[2][SLAB * 16 * CROW];
  __shared__ int maskL[16 * MROW];
  __shared__ int lastF;
  __shared__ float eend[64];
  __shared__ float rsum[4];

  short8 a00, a01, a10, a11, a20, a21, a30, a31;
  uint2 st0, st1, st2, st3;
  float Slog = 0.f;
  int K = 0, NL = 0;
  const f32x4 zero4 = {0.f, 0.f, 0.f, 0.f};

  const int mm_ = lane & 15, seg_ = lane >> 4;
  const int base_ = (seg_ >> 1) * 32 + (seg_ & 1) * 8;
  const size_t rowoff = (size_t)(16 * g + mm_) * Sn;
  const int ua = (wid == 1) ? 0 : 2;
  float4 A0, A1, A2, A3, A4, A5, A6, A7;
  float4 B0, B1, B2, B3, B4, B5, B6, B7;
  float4 C0, C1, C2, C3, C4, C5, C6, C7;
  float4 D0, D1, D2, D3, D4, D5, D6, D7;

#define LOADS(P, s) do { if ((s) < NSLAB) { \
    int ta_ = tstart + 4 * (s) + ua;  int tb_ = ta_ + 1; \
    ta_ = min(ta_, Sn - 1);  tb_ = min(tb_, Sn - 1); \
    const float* pa_ = em + (rowoff + ta_) * 64 + seg_ * 16; \
    const float* pb_ = em + (rowoff + tb_) * 64 + seg_ * 16; \
    P##0 = *(const float4*)(pa_);      P##1 = *(const float4*)(pa_ + 4); \
    P##2 = *(const float4*)(pa_ + 8);  P##3 = *(const float4*)(pa_ + 12); \
    P##4 = *(const float4*)(pb_);      P##5 = *(const float4*)(pb_ + 4); \
    P##6 = *(const float4*)(pb_ + 8);  P##7 = *(const float4*)(pb_ + 12); } } while (0)

#define CONVW(P, s) do { if ((s) < NSLAB) { \
    short* cb_ = convS[(s) & 1]; \
    uint4 o0_, o1_; \
    o0_.x = pke((P##0).x, (P##0).y); o0_.y = pke((P##0).z, (P##0).w); \
    o1_.x = pke((P##1).x, (P##1).y); o1_.y = pke((P##1).z, (P##1).w); \
    o0_.z = pke((P##2).x, (P##2).y); o0_.w = pke((P##2).z, (P##2).w); \
    o1_.z = pke((P##3).x, (P##3).y); o1_.w = pke((P##3).z, (P##3).w); \
    short* cw_ = cb_ + (ua * 16 + mm_) * CROW + base_; \
    *(uint4*)(cw_) = o0_;  *(uint4*)(cw_ + 16) = o1_; \
    o0_.x = pke((P##4).x, (P##4).y); o0_.y = pke((P##4).z, (P##4).w); \
    o1_.x = pke((P##5).x, (P##5).y); o1_.y = pke((P##5).z, (P##5).w); \
    o0_.z = pke((P##6).x, (P##6).y); o0_.w = pke((P##6).z, (P##6).w); \
    o1_.z = pke((P##7).x, (P##7).y); o1_.w = pke((P##7).z, (P##7).w); \
    cw_ = cb_ + ((ua + 1) * 16 + mm_) * CROW + base_; \
    *(uint4*)(cw_) = o0_;  *(uint4*)(cw_ + 16) = o1_; } } while (0)

  if (wid == 0) {
#define LOADA(tm, kc, dst) { \
    _Pragma("unroll") for (int jj = 0; jj < 8; ++jj) { \
      int kk = kc * 32 + q * 8 + jj; \
      dst[jj] = (short)f2bf_rne(__expf(trans[kk * Tn + (32 * ((tm) >> 1) + 4 * ((tm) & 1) + mrow)])); \
    } }
    LOADA(0, 0, a00) LOADA(0, 1, a01) LOADA(1, 0, a10) LOADA(1, 1, a11)
    LOADA(2, 0, a20) LOADA(2, 1, a21) LOADA(3, 0, a30) LOADA(3, 1, a31)
#undef LOADA
    if (c == 0) {
#define INIT0(off, ss) { \
      float4 sv = *(const float4*)(startt + (off)); \
      float4 ev = *(const float4*)(em + (size_t)(16 * g + m) * Sn * Tn + (off)); \
      ss.x = (unsigned)f2bf_rne(__expf(sv.x + ev.x)) | \
             ((unsigned)f2bf_rne(__expf(sv.y + ev.y)) << 16); \
      ss.y = (unsigned)f2bf_rne(__expf(sv.z + ev.z)) | \
             ((unsigned)f2bf_rne(__expf(sv.w + ev.w)) << 16); }
      INIT0(8 * q, st0) INIT0(8 * q + 4, st1)
      INIT0(32 + 8 * q, st2) INIT0(36 + 8 * q, st3)
#undef INIT0
    } else {
      st0.x = 0x3F803F80u; st0.y = 0x3F803F80u; st1 = st0; st2 = st0; st3 = st0;
    }
  } else if (wid == 3) {
    for (int mm = 0; mm < 16; ++mm) {
      gl_lds4(mask + (size_t)(16 * g + mm) * Sn + tstart + lane,
              (void*)(maskL + mm * MROW));
      bool special = (c == NCH - 1) && (g == 15) && (mm == 15);
      if (!special)
        gl_lds4(mask + (size_t)(16 * g + mm) * Sn + tstart + 64 + lane,
                (void*)(maskL + mm * MROW + 64));
    }
    {
      const int bm = 16 * g + m;
      const int* tg = tags + (size_t)bm * Sn;
      const int* mkb = mask + (size_t)bm * Sn;
      const float* emb = em + (size_t)bm * Sn * Tn;
      float acc = 0.f;
      int cntg = 0;
      #pragma unroll 4
      for (int i = 0; i < 16; ++i) {
        int t = t0 + q + 4 * i;
        bool ok = t < t0 + Lc;
        int ts = ok ? t : t0;
        int mv = mkb[ts];
        int tp = tg[ts - 1], tc = tg[ts];
        float w = trans[tp * Tn + tc] + emb[(size_t)ts * Tn + tc];
        acc += (ok && mv) ? w : 0.f;
        cntg += ok ? mv : 0;
      }
      acc += __shfl_xor(acc, 16); acc += __shfl_xor(acc, 32);
      cntg += __shfl_xor(cntg, 16); cntg += __shfl_xor(cntg, 32);
      if (q == 0) { wsGold[c * 256 + bm] = acc; wsM[c * 256 + bm] = cntg; }
    }
    if (c == NCH - 1 && g == 15) {
      int t = tstart + 64 + lane;
      if (t < Sn) maskL[15 * MROW + 64 + lane] = mask[(size_t)255 * Sn + t];
    }
    asm volatile("s_waitcnt vmcnt(0) lgkmcnt(0)" ::: "memory");
  } else {
    LOADS(A, 0);
    LOADS(B, 1);
    LOADS(C, 2);
    LOADS(D, 3);
    CONVW(A, 0);
    asm volatile("s_waitcnt lgkmcnt(0)" ::: "memory");
  }
  __builtin_amdgcn_s_barrier();
  asm volatile("" ::: "memory");

#define UNP(ss, x0, x1, x2, x3) \
  x0 = __uint_as_float(ss.x << 16); x1 = __uint_as_float(ss.x & 0xffff0000u); \
  x2 = __uint_as_float(ss.y << 16); x3 = __uint_as_float(ss.y & 0xffff0000u);

  auto renorm = [&](int ttz) {
    float x00, x01, x02, x03, x10, x11, x12, x13;
    float x20, x21, x22, x23, x30, x31, x32, x33;
    UNP(st0, x00, x01, x02, x03) UNP(st1, x10, x11, x12, x13)
    UNP(st2, x20, x21, x22, x23) UNP(st3, x30, x31, x32, x33)
    float sm = (((x00 + x01) + (x02 + x03)) + ((x10 + x11) + (x12 + x13)))
             + (((x20 + x21) + (x22 + x23)) + ((x30 + x31) + (x32 + x33)));
    sm += __shfl_xor(sm, 16); sm += __shfl_xor(sm, 32);
    if (c != 0 && ttz == BURN) { Slog = __logf(sm); K = 0; NL = 0; }
    int k = 127 - (int)((__float_as_uint(sm) >> 23) & 255u);
    float fk = __uint_as_float((unsigned)(127 + k) << 23);
    x00 *= fk; x01 *= fk; x02 *= fk; x03 *= fk;
    x10 *= fk; x11 *= fk; x12 *= fk; x13 *= fk;
    x20 *= fk; x21 *= fk; x22 *= fk; x23 *= fk;
    x30 *= fk; x31 *= fk; x32 *= fk; x33 *= fk;
    st0.x = pk2(x01, x00); st0.y = pk2(x03, x02);
    st1.x = pk2(x11, x10); st1.y = pk2(x13, x12);
    st2.x = pk2(x21, x20); st2.y = pk2(x23, x22);
    st3.x = pk2(x31, x30); st3.y = pk2(x33, x32);
    K += k;
  };

  auto scan_step = [&](const short* ep, int tt) {
    uint2 eu0 = *(const uint2*)(ep + 0 + 4 * q);
    uint2 eu1 = *(const uint2*)(ep + 16 + 4 * q);
    uint2 eu2 = *(const uint2*)(ep + 32 + 4 * q);
    uint2 eu3 = *(const uint2*)(ep + 48 + 4 * q);
    int mv = maskL[m * MROW + tt];
    short8 b0 = cat4(st0, st1);
    short8 b1 = cat4(st2, st3);
    f32x4 d0 = __builtin_amdgcn_mfma_f32_16x16x32_bf16(a00, b0, zero4, 0, 0, 0);
    f32x4 d1 = __builtin_amdgcn_mfma_f32_16x16x32_bf16(a10, b0, zero4, 0, 0, 0);
    f32x4 d2 = __builtin_amdgcn_mfma_f32_16x16x32_bf16(a20, b0, zero4, 0, 0, 0);
    f32x4 d3 = __builtin_amdgcn_mfma_f32_16x16x32_bf16(a30, b0, zero4, 0, 0, 0);
    d0 = __builtin_amdgcn_mfma_f32_16x16x32_bf16(a01, b1, d0, 0, 0, 0);
    d1 = __builtin_amdgcn_mfma_f32_16x16x32_bf16(a11, b1, d1, 0, 0, 0);
    d2 = __builtin_amdgcn_mfma_f32_16x16x32_bf16(a21, b1, d2, 0, 0, 0);
    d3 = __builtin_amdgcn_mfma_f32_16x16x32_bf16(a31, b1, d3, 0, 0, 0);
    const bool live = (mv != 0);
#define EPI(dd, eu, ss) { \
    float e0 = __uint_as_float(eu.x << 16); \
    float e1 = __uint_as_float(eu.x & 0xffff0000u); \
    float e2 = __uint_as_float(eu.y << 16); \
    float e3 = __uint_as_float(eu.y & 0xffff0000u); \
    unsigned nx = pk2(dd[1] * e1, dd[0] * e0); \
    unsigned ny = pk2(dd[3] * e3, dd[2] * e2); \
    ss.x = live ? nx : ss.x; \
    ss.y = live ? ny : ss.y; }
    EPI(d0, eu0, st0) EPI(d1, eu1, st1) EPI(d2, eu2, st2) EPI(d3, eu3, st3)
#undef EPI
    NL += (live && tt >= Wc) ? 1 : 0;
  };

  const int RT = (TOT - 4) >> 2;
  for (int r = 0; r < NSLAB; ++r) {
    if (wid == 0) {
      if ((r & 1) == 0) renorm(4 * r);
      const short* cbase = convS[r & 1];
      if (r < RT) {
        #pragma unroll
        for (int u = 0; u < SLAB; ++u)
          scan_step(cbase + (u * 16 + m) * CROW, 4 * r + u);
      } else {
        #pragma unroll
        for (int u = 0; u < SLAB; ++u)
          if (4 * r + u < TOT)
            scan_step(cbase + (u * 16 + m) * CROW, 4 * r + u);
      }
    } else if (wid == 1 || wid == 2) {
      switch (r & 3) {
        case 0: LOADS(A, r + 4); CONVW(B, r + 1); break;
        case 1: LOADS(B, r + 4); CONVW(C, r + 1); break;
        case 2: LOADS(C, r + 4); CONVW(D, r + 1); break;
        default: LOADS(D, r + 4); CONVW(A, r + 1); break;
      }
      asm volatile("s_waitcnt lgkmcnt(0)" ::: "memory");
    }
    __builtin_amdgcn_s_barrier();
    asm volatile("" ::: "memory");
  }
#undef LOADS
#undef CONVW

  if (wid == 0) {
    float x00, x01, x02, x03, x10, x11, x12, x13;
    float x20, x21, x22, x23, x30, x31, x32, x33;
    UNP(st0, x00, x01, x02, x03) UNP(st1, x10, x11, x12, x13)
    UNP(st2, x20, x21, x22, x23) UNP(st3, x30, x31, x32, x33)
    float sm = (((x00 + x01) + (x02 + x03)) + ((x10 + x11) + (x12 + x13)))
             + (((x20 + x21) + (x22 + x23)) + ((x30 + x31) + (x32 + x33)));
    sm += __shfl_xor(sm, 16); sm += __shfl_xor(sm, 32);
    const int bm = 16 * g + m;
    float L = __logf(sm) - Slog + LN2 * (float)(7 * NL - K);
    if (q == 0) wsL[c * 256 + bm] = L;
    if (c == NCH - 1) {
      if (q == 0) wsSE[bm] = __logf(sm);
      wsA[(8 * q + 0) * 256 + bm] = x00;  wsA[(8 * q + 1) * 256 + bm] = x01;
      wsA[(8 * q + 2) * 256 + bm] = x02;  wsA[(8 * q + 3) * 256 + bm] = x03;
      wsA[(8 * q + 4) * 256 + bm] = x10;  wsA[(8 * q + 5) * 256 + bm] = x11;
      wsA[(8 * q + 6) * 256 + bm] = x12;  wsA[(8 * q + 7) * 256 + bm] = x13;
      wsA[(32 + 8 * q + 0) * 256 + bm] = x20; wsA[(32 + 8 * q + 1) * 256 + bm] = x21;
      wsA[(32 + 8 * q + 2) * 256 + bm] = x22; wsA[(32 + 8 * q + 3) * 256 + bm] = x23;
      wsA[(36 + 8 * q + 0) * 256 + bm] = x30; wsA[(36 + 8 * q + 1) * 256 + bm] = x31;
      wsA[(36 + 8 * q + 2) * 256 + bm] = x32; wsA[(36 + 8 * q + 3) * 256 + bm] = x33;
    }
  }
#undef UNP

  __threadfence();
  __syncthreads();
  if (tid == 0) lastF = (atomicAdd(cnt, 1) == 255) ? 1 : 0;
  __syncthreads();
  if (lastF) {
    __threadfence();
    if (tid < 64) eend[tid] = __expf(endt[tid]);
    __syncthreads();
    float vsum = 0.f;
    for (int bb = tid; bb < Bn; bb += 256) {
      float sumL = 0.f, gold = 0.f;
      int msum = 0;
      #pragma unroll
      for (int cc = 0; cc < NCH; ++cc) {
        sumL += wsL[cc * 256 + bb];
        gold += wsGold[cc * 256 + bb];
        msum += wsM[cc * 256 + bb];
      }
      msum += mask[(size_t)bb * Sn];
      float se = 0.f;
      for (int jj = 0; jj < Tn; ++jj) se += wsA[jj * 256 + bb] * eend[jj];
      float logZ = sumL + __logf(se) - wsSE[bb];
      int tg0 = tags[(size_t)bb * Sn];
      int lastTag = tags[(size_t)bb * Sn + (msum - 1)];
      gold += startt[tg0] + em[(size_t)bb * Sn * Tn + tg0] + endt[lastTag];
      vsum += logZ - gold;
    }
    #pragma unroll
    for (int o = 32; o > 0; o >>= 1) vsum += __shfl_xor(vsum, o, 64);
    if (lane == 0) rsum[wid] = vsum;
    __syncthreads();
    if (tid == 0) out[0] = (rsum[0] + rsum[1] + rsum[2] + rsum[3]) * (1.0f / Bn);
  }
}

extern "C" void kernel_launch(void* const* d_in, const int* in_sizes, int n_in,
                              void* d_out, int out_size, void* d_ws, size_t ws_size,
                              hipStream_t stream) {
  const float* em     = (const float*)d_in[0];
  const int*   tags   = (const int*)d_in[1];
  const int*   mask   = (const int*)d_in[2];
  const float* trans  = (const float*)d_in[3];
  const float* startt = (const float*)d_in[4];
  const float* endt   = (const float*)d_in[5];
  float* out = (float*)d_out;

  float* wsL    = (float*)d_ws;               // [16*256]
  float* wsGold = wsL + NCH * 256;            // [16*256]
  int*   wsM    = (int*)(wsGold + NCH * 256); // [16*256]
  float* wsSE   = (float*)(wsM + NCH * 256);  // [256]
  float* wsA    = wsSE + 256;                 // [64*256]
  int*   cnt    = (int*)(wsA + 64 * 256);     // [1] last-block counter

  size_t off = (size_t)((char*)(cnt + 1) - (char*)d_ws);
  off = (off + 255) & ~(size_t)255;
  short* em2 = (short*)((char*)d_ws + off);   // [256*1024*64] bf16 (33.5 MB)
  const size_t need = off + (size_t)Bn * Sn * Tn * sizeof(short);

  hipMemsetAsync(cnt, 0, sizeof(int), stream);  // ws is poisoned 0xAA pre-launch
  if (ws_size >= need) {
    crf_prep<<<4096, 256, 0, stream>>>(em, em2);
    crf_scan2<<<256, 128, 0, stream>>>(em, tags, mask, trans, startt, endt, em2,
                                       wsL, wsGold, wsM, wsSE, wsA, cnt, out);
  } else {  // fallback: best-known single-kernel (R8)
    crf_scan_fb<<<256, 256, 0, stream>>>(em, tags, mask, trans, startt, endt,
                                         wsL, wsGold, wsM, wsSE, wsA, cnt, out);
  }
}

// Round 12
// 167.698 us; speedup vs baseline: 1.0040x; 1.0040x over previous
//
#include <hip/hip_runtime.h>

#define Bn 256
#define Sn 1024
#define Tn 64
#define NCH 16
#define BURN 64
#define SLAB 4
#define CROW 72             // fb kernel: conv bf16 row stride in shorts
#define MROW 129
#define EMROW 65664         // em2 row stride in shorts: Sn*64 + 128 (256B pad
                            // de-aliases the power-of-2 channel/L2-set map)
#define LN2 0.69314718055994531f
#define L7LN2 4.8520302639196169f   // 7*ln2 (lambda = 2^-7 folded into exp)

typedef __attribute__((ext_vector_type(8))) short short8;
typedef __attribute__((ext_vector_type(4))) float f32x4;

__device__ __forceinline__ unsigned short f2bf_rne(float f) {
  unsigned u = __float_as_uint(f);
  u = (u + 0x7fffu + ((u >> 16) & 1u)) >> 16;
  return (unsigned short)u;
}
__device__ __forceinline__ unsigned pk2(float hi, float lo) {
  return __builtin_amdgcn_perm(__float_as_uint(hi), __float_as_uint(lo), 0x07060302);
}
__device__ __forceinline__ unsigned pke(float a, float b) {  // exp+pack 2 bf16
  return (unsigned)f2bf_rne(__expf(a - L7LN2)) |
         ((unsigned)f2bf_rne(__expf(b - L7LN2)) << 16);
}
__device__ __forceinline__ short8 cat4(uint2 a, uint2 b) {
  union { unsigned u[4]; short8 s; } x;
  x.u[0] = a.x; x.u[1] = a.y; x.u[2] = b.x; x.u[3] = b.y;
  return x.s;
}
__device__ __forceinline__ void gl_lds16(const void* src, void* dst) {
  __builtin_amdgcn_global_load_lds(
      (const __attribute__((address_space(1))) void*)src,
      (__attribute__((address_space(3))) void*)dst, 16, 0, 0);
}
__device__ __forceinline__ void gl_lds4(const void* src, void* dst) {
  __builtin_amdgcn_global_load_lds(
      (const __attribute__((address_space(1))) void*)src,
      (__attribute__((address_space(3))) void*)dst, 4, 0, 0);
}

// R12 = R11 + de-aliased em2 row stride. R11 diagnosis: contiguous prep runs
// >1.6 TB/s in this harness while EVERY strided scan variant (R0-R11) pins at
// 0.9-2.6 B/cy/CU -- the common factor is the power-of-2 row stride (256KB
// f32 / 128KB bf16): all 16 rows of a slab load share one HBM-channel/L2-set
// residue -> service serialization no schedule can fix. Fix: pad em2 rows by
// 256B (EMROW) so consecutive rows shift the 256B-granule phase -> a slab
// spreads over 16 residues. Everything else identical to R11.
__global__ __launch_bounds__(256) void crf_prep(const float* __restrict__ em,
                                                short* __restrict__ em2) {
  int idx = blockIdx.x * 256 + threadIdx.x;   // 4096*256 == Bn*Sn*4 exactly
  if (idx >= Bn * Sn * 4) return;
  const int cell = idx >> 2;                  // (b,t)
  const int j = idx & 3;                      // q-quadrant
  const int b = cell >> 10;                   // Sn = 1024
  const int t = cell & 1023;
  const float* src = em + (size_t)cell * 64;
  float4 v0 = *(const float4*)(src + 8 * j);
  float4 v1 = *(const float4*)(src + 8 * j + 4);
  float4 v2 = *(const float4*)(src + 32 + 8 * j);
  float4 v3 = *(const float4*)(src + 32 + 8 * j + 4);
  uint4 O1, O2;
  O1.x = pke(v0.x, v0.y); O1.y = pke(v0.z, v0.w);   // states 8j..8j+3
  O1.z = pke(v1.x, v1.y); O1.w = pke(v1.z, v1.w);   // states 8j+4..8j+7
  O2.x = pke(v2.x, v2.y); O2.y = pke(v2.z, v2.w);   // states 32+8j..+3
  O2.z = pke(v3.x, v3.y); O2.w = pke(v3.z, v3.w);   // states 32+8j+4..+7
  short* dst = em2 + (size_t)b * EMROW + (size_t)t * 64;
  const int sw = (b & 7) << 3;                // 16B-granule XOR (8 shorts)
  *(uint4*)(dst + ((j * 16) ^ sw)) = O1;      // eu0|eu1 of lane q=j
  *(uint4*)(dst + ((j * 16 + 8) ^ sw)) = O2;  // eu2|eu3 of lane q=j
}

// ======================= kernel 2: bf16 scan ============================
// 256 blocks x 2 waves. wave0: unchanged MFMA scan reading bf16 straight
// from a 4-deep LDS ring. wave1: pure producer -- 8 gl_lds16 per slab,
// slab r+3 issued at round r, counted in-order vmcnt (14/6/0).
__global__ __launch_bounds__(128, 1) void crf_scan2(
    const float* __restrict__ em, const int* __restrict__ tags,
    const int* __restrict__ mask, const float* __restrict__ trans,
    const float* __restrict__ startt, const float* __restrict__ endt,
    const short* __restrict__ em2,
    float* __restrict__ wsL, float* __restrict__ wsGold,
    int* __restrict__ wsM, float* __restrict__ wsSE, float* __restrict__ wsA,
    int* __restrict__ cnt, float* __restrict__ out) {
  const int g = blockIdx.x & 15;
  const int c = blockIdx.x >> 4;
  const int Wc = (c == 0) ? 0 : BURN;
  const int Lc = (c == NCH - 1) ? 63 : 64;
  const int TOT = Wc + Lc;
  const int NSLAB = (TOT + SLAB - 1) / SLAB;
  const int t0 = 64 * c + 1;
  const int tstart = t0 - Wc;
  const int tid = threadIdx.x;
  const int wid = tid >> 6;
  const int lane = tid & 63;
  const int m = lane & 15;
  const int q = lane >> 4;
  const int mrow = 8 * (m >> 2) + (m & 3);  // permuted A-row base
  const int swm = (m & 7) << 3;             // matches prep's XOR swizzle
  const int hi = lane >> 3, inner = lane & 7;  // producer lane split

  __shared__ __align__(16) short ring[4][SLAB * 16 * 64];  // 32 KB bf16 em
  __shared__ int maskL[16 * MROW];                         // 8.3 KB
  __shared__ int lastF;
  __shared__ float eend[64];
  __shared__ float rsum[2];

  short8 a00, a01, a10, a11, a20, a21, a30, a31;
  uint2 st0, st1, st2, st3;
  float Slog = 0.f;
  int K = 0, NL = 0;
  const f32x4 zero4 = {0.f, 0.f, 0.f, 0.f};

  auto issue_slab = [&](int s) {   // 2*rem gl_lds16 (8 full / 6 tail)
    if (s >= NSLAB) return;
    short* dstb = ring[s & 3];
    const int rem = min(SLAB, TOT - 4 * s);
    const int Ts = tstart + 4 * s;
    for (int u = 0; u < rem; ++u)
      for (int hf = 0; hf < 2; ++hf)
        gl_lds16(em2 + (size_t)(16 * g + hf * 8 + hi) * EMROW
                     + (size_t)(Ts + u) * 64 + inner * 8,
                 dstb + (u * 16 + hf * 8) * 64);
  };

  // ================= prologue =================
  if (wid == 0) {
#define LOADA(tm, kc, dst) { \
    _Pragma("unroll") for (int jj = 0; jj < 8; ++jj) { \
      int kk = kc * 32 + q * 8 + jj; \
      dst[jj] = (short)f2bf_rne(__expf(trans[kk * Tn + (32 * ((tm) >> 1) + 4 * ((tm) & 1) + mrow)])); \
    } }
    LOADA(0, 0, a00) LOADA(0, 1, a01) LOADA(1, 0, a10) LOADA(1, 1, a11)
    LOADA(2, 0, a20) LOADA(2, 1, a21) LOADA(3, 0, a30) LOADA(3, 1, a31)
#undef LOADA
    if (c == 0) {  // exact alpha_0 = exp(startt + em[:,0,:]), permuted slots
#define INIT0(off, ss) { \
      float4 sv = *(const float4*)(startt + (off)); \
      float4 ev = *(const float4*)(em + (size_t)(16 * g + m) * Sn * Tn + (off)); \
      ss.x = (unsigned)f2bf_rne(__expf(sv.x + ev.x)) | \
             ((unsigned)f2bf_rne(__expf(sv.y + ev.y)) << 16); \
      ss.y = (unsigned)f2bf_rne(__expf(sv.z + ev.z)) | \
             ((unsigned)f2bf_rne(__expf(sv.w + ev.w)) << 16); }
      INIT0(8 * q, st0) INIT0(8 * q + 4, st1)
      INIT0(32 + 8 * q, st2) INIT0(36 + 8 * q, st3)
#undef INIT0
    } else {
      st0.x = 0x3F803F80u; st0.y = 0x3F803F80u; st1 = st0; st2 = st0; st3 = st0;
    }
    if (c == NCH - 1 && g == 15) {  // mask repair (wave1 skips this slot)
      int t = tstart + 64 + lane;
      if (t < Sn) maskL[15 * MROW + 64 + lane] = mask[(size_t)255 * Sn + t];
    }
    asm volatile("s_waitcnt vmcnt(0) lgkmcnt(0)" ::: "memory");
  } else {
    // mask staging (gl_lds, oldest in queue)
    for (int mm = 0; mm < 16; ++mm) {
      gl_lds4(mask + (size_t)(16 * g + mm) * Sn + tstart + lane,
              (void*)(maskL + mm * MROW));
      bool special = (c == NCH - 1) && (g == 15) && (mm == 15);  // OOB t=1024
      if (!special)
        gl_lds4(mask + (size_t)(16 * g + mm) * Sn + tstart + 64 + lane,
                (void*)(maskL + mm * MROW + 64));
    }
    // gold partials (plain loads; consumption drains them + older mask)
    {
      const int bm = 16 * g + m;
      const int* tg = tags + (size_t)bm * Sn;
      const int* mkb = mask + (size_t)bm * Sn;
      const float* emb = em + (size_t)bm * Sn * Tn;
      float acc = 0.f;
      int cntg = 0;
      #pragma unroll 4
      for (int i = 0; i < 16; ++i) {
        int t = t0 + q + 4 * i;
        bool ok = t < t0 + Lc;
        int ts = ok ? t : t0;
        int mv = mkb[ts];
        int tp = tg[ts - 1], tc = tg[ts];
        float w = trans[tp * Tn + tc] + emb[(size_t)ts * Tn + tc];
        acc += (ok && mv) ? w : 0.f;
        cntg += ok ? mv : 0;
      }
      acc += __shfl_xor(acc, 16); acc += __shfl_xor(acc, 32);
      cntg += __shfl_xor(cntg, 16); cntg += __shfl_xor(cntg, 32);
      if (q == 0) { wsGold[c * 256 + bm] = acc; wsM[c * 256 + bm] = cntg; }
    }
    asm volatile("s_waitcnt vmcnt(0)" ::: "memory");  // mask+gold done
    issue_slab(0); issue_slab(1); issue_slab(2);
    asm volatile("s_waitcnt vmcnt(16)" ::: "memory"); // slab0 done; 1,2 fly
  }
  __builtin_amdgcn_s_barrier();   // B1: ring[0] + maskL ready
  asm volatile("" ::: "memory");

  // ================= rounds =================
#define UNP(ss, x0, x1, x2, x3) \
  x0 = __uint_as_float(ss.x << 16); x1 = __uint_as_float(ss.x & 0xffff0000u); \
  x2 = __uint_as_float(ss.y << 16); x3 = __uint_as_float(ss.y & 0xffff0000u);

  auto renorm = [&](int ttz) {
    float x00, x01, x02, x03, x10, x11, x12, x13;
    float x20, x21, x22, x23, x30, x31, x32, x33;
    UNP(st0, x00, x01, x02, x03) UNP(st1, x10, x11, x12, x13)
    UNP(st2, x20, x21, x22, x23) UNP(st3, x30, x31, x32, x33)
    float sm = (((x00 + x01) + (x02 + x03)) + ((x10 + x11) + (x12 + x13)))
             + (((x20 + x21) + (x22 + x23)) + ((x30 + x31) + (x32 + x33)));
    sm += __shfl_xor(sm, 16); sm += __shfl_xor(sm, 32);
    if (c != 0 && ttz == BURN) { Slog = __logf(sm); K = 0; NL = 0; }
    int k = 127 - (int)((__float_as_uint(sm) >> 23) & 255u);
    float fk = __uint_as_float((unsigned)(127 + k) << 23);
    x00 *= fk; x01 *= fk; x02 *= fk; x03 *= fk;
    x10 *= fk; x11 *= fk; x12 *= fk; x13 *= fk;
    x20 *= fk; x21 *= fk; x22 *= fk; x23 *= fk;
    x30 *= fk; x31 *= fk; x32 *= fk; x33 *= fk;
    st0.x = pk2(x01, x00); st0.y = pk2(x03, x02);
    st1.x = pk2(x11, x10); st1.y = pk2(x13, x12);
    st2.x = pk2(x21, x20); st2.y = pk2(x23, x22);
    st3.x = pk2(x31, x30); st3.y = pk2(x33, x32);
    K += k;
  };

  auto scan_step = [&](const short* cellb, int tt) {
    uint4 E01 = *(const uint4*)(cellb + ((q * 16) ^ swm));
    uint4 E23 = *(const uint4*)(cellb + ((q * 16 + 8) ^ swm));
    uint2 eu0; eu0.x = E01.x; eu0.y = E01.y;
    uint2 eu1; eu1.x = E01.z; eu1.y = E01.w;
    uint2 eu2; eu2.x = E23.x; eu2.y = E23.y;
    uint2 eu3; eu3.x = E23.z; eu3.y = E23.w;
    int mv = maskL[m * MROW + tt];
    short8 b0 = cat4(st0, st1);
    short8 b1 = cat4(st2, st3);
    f32x4 d0 = __builtin_amdgcn_mfma_f32_16x16x32_bf16(a00, b0, zero4, 0, 0, 0);
    f32x4 d1 = __builtin_amdgcn_mfma_f32_16x16x32_bf16(a10, b0, zero4, 0, 0, 0);
    f32x4 d2 = __builtin_amdgcn_mfma_f32_16x16x32_bf16(a20, b0, zero4, 0, 0, 0);
    f32x4 d3 = __builtin_amdgcn_mfma_f32_16x16x32_bf16(a30, b0, zero4, 0, 0, 0);
    d0 = __builtin_amdgcn_mfma_f32_16x16x32_bf16(a01, b1, d0, 0, 0, 0);
    d1 = __builtin_amdgcn_mfma_f32_16x16x32_bf16(a11, b1, d1, 0, 0, 0);
    d2 = __builtin_amdgcn_mfma_f32_16x16x32_bf16(a21, b1, d2, 0, 0, 0);
    d3 = __builtin_amdgcn_mfma_f32_16x16x32_bf16(a31, b1, d3, 0, 0, 0);
    const bool live = (mv != 0);
#define EPI(dd, eu, ss) { \
    float e0 = __uint_as_float(eu.x << 16); \
    float e1 = __uint_as_float(eu.x & 0xffff0000u); \
    float e2 = __uint_as_float(eu.y << 16); \
    float e3 = __uint_as_float(eu.y & 0xffff0000u); \
    unsigned nx = pk2(dd[1] * e1, dd[0] * e0); \
    unsigned ny = pk2(dd[3] * e3, dd[2] * e2); \
    ss.x = live ? nx : ss.x; \
    ss.y = live ? ny : ss.y; }
    EPI(d0, eu0, st0) EPI(d1, eu1, st1) EPI(d2, eu2, st2) EPI(d3, eu3, st3)
#undef EPI
    NL += (live && tt >= Wc) ? 1 : 0;
  };

  const int RT = (TOT - 4) >> 2;
  for (int r = 0; r < NSLAB; ++r) {
    if (wid == 0) {
      if ((r & 1) == 0) renorm(4 * r);
      const short* rb = ring[r & 3];
      if (r < RT) {
        #pragma unroll
        for (int u = 0; u < SLAB; ++u)
          scan_step(rb + (u * 16 + m) * 64, 4 * r + u);
      } else {
        #pragma unroll
        for (int u = 0; u < SLAB; ++u)
          if (4 * r + u < TOT)
            scan_step(rb + (u * 16 + m) * 64, 4 * r + u);
      }
    } else {
      issue_slab(r + 3);   // into ring[(r+3)&3]; ring[r&3] read this round
      // in-order vmcnt: drain slab r+1 (8, or tail's exact count); keep
      // r+2,r+3 in flight. 14 handles the 6-load tail slab exactly.
      if (r + 3 < NSLAB)      asm volatile("s_waitcnt vmcnt(14)" ::: "memory");
      else if (r + 2 < NSLAB) asm volatile("s_waitcnt vmcnt(6)" ::: "memory");
      else                    asm volatile("s_waitcnt vmcnt(0)" ::: "memory");
    }
    __builtin_amdgcn_s_barrier();
    asm volatile("" ::: "memory");
  }

  // ================= per-chunk outputs =================
  if (wid == 0) {
    float x00, x01, x02, x03, x10, x11, x12, x13;
    float x20, x21, x22, x23, x30, x31, x32, x33;
    UNP(st0, x00, x01, x02, x03) UNP(st1, x10, x11, x12, x13)
    UNP(st2, x20, x21, x22, x23) UNP(st3, x30, x31, x32, x33)
    float sm = (((x00 + x01) + (x02 + x03)) + ((x10 + x11) + (x12 + x13)))
             + (((x20 + x21) + (x22 + x23)) + ((x30 + x31) + (x32 + x33)));
    sm += __shfl_xor(sm, 16); sm += __shfl_xor(sm, 32);
    const int bm = 16 * g + m;
    float L = __logf(sm) - Slog + LN2 * (float)(7 * NL - K);
    if (q == 0) wsL[c * 256 + bm] = L;
    if (c == NCH - 1) {
      if (q == 0) wsSE[bm] = __logf(sm);
      wsA[(8 * q + 0) * 256 + bm] = x00;  wsA[(8 * q + 1) * 256 + bm] = x01;
      wsA[(8 * q + 2) * 256 + bm] = x02;  wsA[(8 * q + 3) * 256 + bm] = x03;
      wsA[(8 * q + 4) * 256 + bm] = x10;  wsA[(8 * q + 5) * 256 + bm] = x11;
      wsA[(8 * q + 6) * 256 + bm] = x12;  wsA[(8 * q + 7) * 256 + bm] = x13;
      wsA[(32 + 8 * q + 0) * 256 + bm] = x20; wsA[(32 + 8 * q + 1) * 256 + bm] = x21;
      wsA[(32 + 8 * q + 2) * 256 + bm] = x22; wsA[(32 + 8 * q + 3) * 256 + bm] = x23;
      wsA[(36 + 8 * q + 0) * 256 + bm] = x30; wsA[(36 + 8 * q + 1) * 256 + bm] = x31;
      wsA[(36 + 8 * q + 2) * 256 + bm] = x32; wsA[(36 + 8 * q + 3) * 256 + bm] = x33;
    }
  }
#undef UNP

  // ================= fused finale (last block) =================
  __threadfence();
  __syncthreads();
  if (tid == 0) lastF = (atomicAdd(cnt, 1) == 255) ? 1 : 0;
  __syncthreads();
  if (lastF) {
    __threadfence();
    if (tid < 64) eend[tid] = __expf(endt[tid]);
    __syncthreads();
    float vsum = 0.f;
    for (int bb = tid; bb < Bn; bb += 128) {
      float sumL = 0.f, gold = 0.f;
      int msum = 0;
      #pragma unroll
      for (int cc = 0; cc < NCH; ++cc) {
        sumL += wsL[cc * 256 + bb];
        gold += wsGold[cc * 256 + bb];
        msum += wsM[cc * 256 + bb];
      }
      msum += mask[(size_t)bb * Sn];
      float se = 0.f;
      for (int jj = 0; jj < Tn; ++jj) se += wsA[jj * 256 + bb] * eend[jj];
      float logZ = sumL + __logf(se) - wsSE[bb];
      int tg0 = tags[(size_t)bb * Sn];
      int lastTag = tags[(size_t)bb * Sn + (msum - 1)];
      gold += startt[tg0] + em[(size_t)bb * Sn * Tn + tg0] + endt[lastTag];
      vsum += logZ - gold;
    }
    #pragma unroll
    for (int o = 32; o > 0; o >>= 1) vsum += __shfl_xor(vsum, o, 64);
    if (lane == 0) rsum[wid] = vsum;
    __syncthreads();
    if (tid == 0) out[0] = (rsum[0] + rsum[1]) * (1.0f / Bn);
  }
}

// =============== fallback: R8 kernel verbatim (ws too small) ===============
__global__ __launch_bounds__(256, 1) void crf_scan_fb(
    const float* __restrict__ em, const int* __restrict__ tags,
    const int* __restrict__ mask, const float* __restrict__ trans,
    const float* __restrict__ startt, const float* __restrict__ endt,
    float* __restrict__ wsL, float* __restrict__ wsGold,
    int* __restrict__ wsM, float* __restrict__ wsSE, float* __restrict__ wsA,
    int* __restrict__ cnt, float* __restrict__ out) {
  const int g = blockIdx.x & 15;
  const int c = blockIdx.x >> 4;
  const int Wc = (c == 0) ? 0 : BURN;
  const int Lc = (c == NCH - 1) ? 63 : 64;
  const int TOT = Wc + Lc;
  const int NSLAB = (TOT + SLAB - 1) / SLAB;
  const int t0 = 64 * c + 1;
  const int tstart = t0 - Wc;
  const int tid = threadIdx.x;
  const int wid = tid >> 6;
  const int lane = tid & 63;
  const int m = lane & 15;
  const int q = lane >> 4;
  const int mrow = 8 * (m >> 2) + (m & 3);

  __shared__ __align__(16) short convS[2][SLAB * 16 * CROW];
  __shared__ int maskL[16 * MROW];
  __shared__ int lastF;
  __shared__ float eend[64];
  __shared__ float rsum[4];

  short8 a00, a01, a10, a11, a20, a21, a30, a31;
  uint2 st0, st1, st2, st3;
  float Slog = 0.f;
  int K = 0, NL = 0;
  const f32x4 zero4 = {0.f, 0.f, 0.f, 0.f};

  const int mm_ = lane & 15, seg_ = lane >> 4;
  const int base_ = (seg_ >> 1) * 32 + (seg_ & 1) * 8;
  const size_t rowoff = (size_t)(16 * g + mm_) * Sn;
  const int ua = (wid == 1) ? 0 : 2;
  float4 A0, A1, A2, A3, A4, A5, A6, A7;
  float4 B0, B1, B2, B3, B4, B5, B6, B7;
  float4 C0, C1, C2, C3, C4, C5, C6, C7;
  float4 D0, D1, D2, D3, D4, D5, D6, D7;

#define LOADS(P, s) do { if ((s) < NSLAB) { \
    int ta_ = tstart + 4 * (s) + ua;  int tb_ = ta_ + 1; \
    ta_ = min(ta_, Sn - 1);  tb_ = min(tb_, Sn - 1); \
    const float* pa_ = em + (rowoff + ta_) * 64 + seg_ * 16; \
    const float* pb_ = em + (rowoff + tb_) * 64 + seg_ * 16; \
    P##0 = *(const float4*)(pa_);      P##1 = *(const float4*)(pa_ + 4); \
    P##2 = *(const float4*)(pa_ + 8);  P##3 = *(const float4*)(pa_ + 12); \
    P##4 = *(const float4*)(pb_);      P##5 = *(const float4*)(pb_ + 4); \
    P##6 = *(const float4*)(pb_ + 8);  P##7 = *(const float4*)(pb_ + 12); } } while (0)

#define CONVW(P, s) do { if ((s) < NSLAB) { \
    short* cb_ = convS[(s) & 1]; \
    uint4 o0_, o1_; \
    o0_.x = pke((P##0).x, (P##0).y); o0_.y = pke((P##0).z, (P##0).w); \
    o1_.x = pke((P##1).x, (P##1).y); o1_.y = pke((P##1).z, (P##1).w); \
    o0_.z = pke((P##2).x, (P##2).y); o0_.w = pke((P##2).z, (P##2).w); \
    o1_.z = pke((P##3).x, (P##3).y); o1_.w = pke((P##3).z, (P##3).w); \
    short* cw_ = cb_ + (ua * 16 + mm_) * CROW + base_; \
    *(uint4*)(cw_) = o0_;  *(uint4*)(cw_ + 16) = o1_; \
    o0_.x = pke((P##4).x, (P##4).y); o0_.y = pke((P##4).z, (P##4).w); \
    o1_.x = pke((P##5).x, (P##5).y); o1_.y = pke((P##5).z, (P##5).w); \
    o0_.z = pke((P##6).x, (P##6).y); o0_.w = pke((P##6).z, (P##6).w); \
    o1_.z = pke((P##7).x, (P##7).y); o1_.w = pke((P##7).z, (P##7).w); \
    cw_ = cb_ + ((ua + 1) * 16 + mm_) * CROW + base_; \
    *(uint4*)(cw_) = o0_;  *(uint4*)(cw_ + 16) = o1_; } } while (0)

  if (wid == 0) {
#define LOADA(tm, kc, dst) { \
    _Pragma("unroll") for (int jj = 0; jj < 8; ++jj) { \
      int kk = kc * 32 + q * 8 + jj; \
      dst[jj] = (short)f2bf_rne(__expf(trans[kk * Tn + (32 * ((tm) >> 1) + 4 * ((tm) & 1) + mrow)])); \
    } }
    LOADA(0, 0, a00) LOADA(0, 1, a01) LOADA(1, 0, a10) LOADA(1, 1, a11)
    LOADA(2, 0, a20) LOADA(2, 1, a21) LOADA(3, 0, a30) LOADA(3, 1, a31)
#undef LOADA
    if (c == 0) {
#define INIT0(off, ss) { \
      float4 sv = *(const float4*)(startt + (off)); \
      float4 ev = *(const float4*)(em + (size_t)(16 * g + m) * Sn * Tn + (off)); \
      ss.x = (unsigned)f2bf_rne(__expf(sv.x + ev.x)) | \
             ((unsigned)f2bf_rne(__expf(sv.y + ev.y)) << 16); \
      ss.y = (unsigned)f2bf_rne(__expf(sv.z + ev.z)) | \
             ((unsigned)f2bf_rne(__expf(sv.w + ev.w)) << 16); }
      INIT0(8 * q, st0) INIT0(8 * q + 4, st1)
      INIT0(32 + 8 * q, st2) INIT0(36 + 8 * q, st3)
#undef INIT0
    } else {
      st0.x = 0x3F803F80u; st0.y = 0x3F803F80u; st1 = st0; st2 = st0; st3 = st0;
    }
  } else if (wid == 3) {
    for (int mm = 0; mm < 16; ++mm) {
      gl_lds4(mask + (size_t)(16 * g + mm) * Sn + tstart + lane,
              (void*)(maskL + mm * MROW));
      bool special = (c == NCH - 1) && (g == 15) && (mm == 15);
      if (!special)
        gl_lds4(mask + (size_t)(16 * g + mm) * Sn + tstart + 64 + lane,
                (void*)(maskL + mm * MROW + 64));
    }
    {
      const int bm = 16 * g + m;
      const int* tg = tags + (size_t)bm * Sn;
      const int* mkb = mask + (size_t)bm * Sn;
      const float* emb = em + (size_t)bm * Sn * Tn;
      float acc = 0.f;
      int cntg = 0;
      #pragma unroll 4
      for (int i = 0; i < 16; ++i) {
        int t = t0 + q + 4 * i;
        bool ok = t < t0 + Lc;
        int ts = ok ? t : t0;
        int mv = mkb[ts];
        int tp = tg[ts - 1], tc = tg[ts];
        float w = trans[tp * Tn + tc] + emb[(size_t)ts * Tn + tc];
        acc += (ok && mv) ? w : 0.f;
        cntg += ok ? mv : 0;
      }
      acc += __shfl_xor(acc, 16); acc += __shfl_xor(acc, 32);
      cntg += __shfl_xor(cntg, 16); cntg += __shfl_xor(cntg, 32);
      if (q == 0) { wsGold[c * 256 + bm] = acc; wsM[c * 256 + bm] = cntg; }
    }
    if (c == NCH - 1 && g == 15) {
      int t = tstart + 64 + lane;
      if (t < Sn) maskL[15 * MROW + 64 + lane] = mask[(size_t)255 * Sn + t];
    }
    asm volatile("s_waitcnt vmcnt(0) lgkmcnt(0)" ::: "memory");
  } else {
    LOADS(A, 0);
    LOADS(B, 1);
    LOADS(C, 2);
    LOADS(D, 3);
    CONVW(A, 0);
    asm volatile("s_waitcnt lgkmcnt(0)" ::: "memory");
  }
  __builtin_amdgcn_s_barrier();
  asm volatile("" ::: "memory");

#define UNP(ss, x0, x1, x2, x3) \
  x0 = __uint_as_float(ss.x << 16); x1 = __uint_as_float(ss.x & 0xffff0000u); \
  x2 = __uint_as_float(ss.y << 16); x3 = __uint_as_float(ss.y & 0xffff0000u);

  auto renorm = [&](int ttz) {
    float x00, x01, x02, x03, x10, x11, x12, x13;
    float x20, x21, x22, x23, x30, x31, x32, x33;
    UNP(st0, x00, x01, x02, x03) UNP(st1, x10, x11, x12, x13)
    UNP(st2, x20, x21, x22, x23) UNP(st3, x30, x31, x32, x33)
    float sm = (((x00 + x01) + (x02 + x03)) + ((x10 + x11) + (x12 + x13)))
             + (((x20 + x21) + (x22 + x23)) + ((x30 + x31) + (x32 + x33)));
    sm += __shfl_xor(sm, 16); sm += __shfl_xor(sm, 32);
    if (c != 0 && ttz == BURN) { Slog = __logf(sm); K = 0; NL = 0; }
    int k = 127 - (int)((__float_as_uint(sm) >> 23) & 255u);
    float fk = __uint_as_float((unsigned)(127 + k) << 23);
    x00 *= fk; x01 *= fk; x02 *= fk; x03 *= fk;
    x10 *= fk; x11 *= fk; x12 *= fk; x13 *= fk;
    x20 *= fk; x21 *= fk; x22 *= fk; x23 *= fk;
    x30 *= fk; x31 *= fk; x32 *= fk; x33 *= fk;
    st0.x = pk2(x01, x00); st0.y = pk2(x03, x02);
    st1.x = pk2(x11, x10); st1.y = pk2(x13, x12);
    st2.x = pk2(x21, x20); st2.y = pk2(x23, x22);
    st3.x = pk2(x31, x30); st3.y = pk2(x33, x32);
    K += k;
  };

  auto scan_step = [&](const short* ep, int tt) {
    uint2 eu0 = *(const uint2*)(ep + 0 + 4 * q);
    uint2 eu1 = *(const uint2*)(ep + 16 + 4 * q);
    uint2 eu2 = *(const uint2*)(ep + 32 + 4 * q);
    uint2 eu3 = *(const uint2*)(ep + 48 + 4 * q);
    int mv = maskL[m * MROW + tt];
    short8 b0 = cat4(st0, st1);
    short8 b1 = cat4(st2, st3);
    f32x4 d0 = __builtin_amdgcn_mfma_f32_16x16x32_bf16(a00, b0, zero4, 0, 0, 0);
    f32x4 d1 = __builtin_amdgcn_mfma_f32_16x16x32_bf16(a10, b0, zero4, 0, 0, 0);
    f32x4 d2 = __builtin_amdgcn_mfma_f32_16x16x32_bf16(a20, b0, zero4, 0, 0, 0);
    f32x4 d3 = __builtin_amdgcn_mfma_f32_16x16x32_bf16(a30, b0, zero4, 0, 0, 0);
    d0 = __builtin_amdgcn_mfma_f32_16x16x32_bf16(a01, b1, d0, 0, 0, 0);
    d1 = __builtin_amdgcn_mfma_f32_16x16x32_bf16(a11, b1, d1, 0, 0, 0);
    d2 = __builtin_amdgcn_mfma_f32_16x16x32_bf16(a21, b1, d2, 0, 0, 0);
    d3 = __builtin_amdgcn_mfma_f32_16x16x32_bf16(a31, b1, d3, 0, 0, 0);
    const bool live = (mv != 0);
#define EPI(dd, eu, ss) { \
    float e0 = __uint_as_float(eu.x << 16); \
    float e1 = __uint_as_float(eu.x & 0xffff0000u); \
    float e2 = __uint_as_float(eu.y << 16); \
    float e3 = __uint_as_float(eu.y & 0xffff0000u); \
    unsigned nx = pk2(dd[1] * e1, dd[0] * e0); \
    unsigned ny = pk2(dd[3] * e3, dd[2] * e2); \
    ss.x = live ? nx : ss.x; \
    ss.y = live ? ny : ss.y; }
    EPI(d0, eu0, st0) EPI(d1, eu1, st1) EPI(d2, eu2, st2) EPI(d3, eu3, st3)
#undef EPI
    NL += (live && tt >= Wc) ? 1 : 0;
  };

  const int RT = (TOT - 4) >> 2;
  for (int r = 0; r < NSLAB; ++r) {
    if (wid == 0) {
      if ((r & 1) == 0) renorm(4 * r);
      const short* cbase = convS[r & 1];
      if (r < RT) {
        #pragma unroll
        for (int u = 0; u < SLAB; ++u)
          scan_step(cbase + (u * 16 + m) * CROW, 4 * r + u);
      } else {
        #pragma unroll
        for (int u = 0; u < SLAB; ++u)
          if (4 * r + u < TOT)
            scan_step(cbase + (u * 16 + m) * CROW, 4 * r + u);
      }
    } else if (wid == 1 || wid == 2) {
      switch (r & 3) {
        case 0: LOADS(A, r + 4); CONVW(B, r + 1); break;
        case 1: LOADS(B, r + 4); CONVW(C, r + 1); break;
        case 2: LOADS(C, r + 4); CONVW(D, r + 1); break;
        default: LOADS(D, r + 4); CONVW(A, r + 1); break;
      }
      asm volatile("s_waitcnt lgkmcnt(0)" ::: "memory");
    }
    __builtin_amdgcn_s_barrier();
    asm volatile("" ::: "memory");
  }
#undef LOADS
#undef CONVW

  if (wid == 0) {
    float x00, x01, x02, x03, x10, x11, x12, x13;
    float x20, x21, x22, x23, x30, x31, x32, x33;
    UNP(st0, x00, x01, x02, x03) UNP(st1, x10, x11, x12, x13)
    UNP(st2, x20, x21, x22, x23) UNP(st3, x30, x31, x32, x33)
    float sm = (((x00 + x01) + (x02 + x03)) + ((x10 + x11) + (x12 + x13)))
             + (((x20 + x21) + (x22 + x23)) + ((x30 + x31) + (x32 + x33)));
    sm += __shfl_xor(sm, 16); sm += __shfl_xor(sm, 32);
    const int bm = 16 * g + m;
    float L = __logf(sm) - Slog + LN2 * (float)(7 * NL - K);
    if (q == 0) wsL[c * 256 + bm] = L;
    if (c == NCH - 1) {
      if (q == 0) wsSE[bm] = __logf(sm);
      wsA[(8 * q + 0) * 256 + bm] = x00;  wsA[(8 * q + 1) * 256 + bm] = x01;
      wsA[(8 * q + 2) * 256 + bm] = x02;  wsA[(8 * q + 3) * 256 + bm] = x03;
      wsA[(8 * q + 4) * 256 + bm] = x10;  wsA[(8 * q + 5) * 256 + bm] = x11;
      wsA[(8 * q + 6) * 256 + bm] = x12;  wsA[(8 * q + 7) * 256 + bm] = x13;
      wsA[(32 + 8 * q + 0) * 256 + bm] = x20; wsA[(32 + 8 * q + 1) * 256 + bm] = x21;
      wsA[(32 + 8 * q + 2) * 256 + bm] = x22; wsA[(32 + 8 * q + 3) * 256 + bm] = x23;
      wsA[(36 + 8 * q + 0) * 256 + bm] = x30; wsA[(36 + 8 * q + 1) * 256 + bm] = x31;
      wsA[(36 + 8 * q + 2) * 256 + bm] = x32; wsA[(36 + 8 * q + 3) * 256 + bm] = x33;
    }
  }
#undef UNP

  __threadfence();
  __syncthreads();
  if (tid == 0) lastF = (atomicAdd(cnt, 1) == 255) ? 1 : 0;
  __syncthreads();
  if (lastF) {
    __threadfence();
    if (tid < 64) eend[tid] = __expf(endt[tid]);
    __syncthreads();
    float vsum = 0.f;
    for (int bb = tid; bb < Bn; bb += 256) {
      float sumL = 0.f, gold = 0.f;
      int msum = 0;
      #pragma unroll
      for (int cc = 0; cc < NCH; ++cc) {
        sumL += wsL[cc * 256 + bb];
        gold += wsGold[cc * 256 + bb];
        msum += wsM[cc * 256 + bb];
      }
      msum += mask[(size_t)bb * Sn];
      float se = 0.f;
      for (int jj = 0; jj < Tn; ++jj) se += wsA[jj * 256 + bb] * eend[jj];
      float logZ = sumL + __logf(se) - wsSE[bb];
      int tg0 = tags[(size_t)bb * Sn];
      int lastTag = tags[(size_t)bb * Sn + (msum - 1)];
      gold += startt[tg0] + em[(size_t)bb * Sn * Tn + tg0] + endt[lastTag];
      vsum += logZ - gold;
    }
    #pragma unroll
    for (int o = 32; o > 0; o >>= 1) vsum += __shfl_xor(vsum, o, 64);
    if (lane == 0) rsum[wid] = vsum;
    __syncthreads();
    if (tid == 0) out[0] = (rsum[0] + rsum[1] + rsum[2] + rsum[3]) * (1.0f / Bn);
  }
}

extern "C" void kernel_launch(void* const* d_in, const int* in_sizes, int n_in,
                              void* d_out, int out_size, void* d_ws, size_t ws_size,
                              hipStream_t stream) {
  const float* em     = (const float*)d_in[0];
  const int*   tags   = (const int*)d_in[1];
  const int*   mask   = (const int*)d_in[2];
  const float* trans  = (const float*)d_in[3];
  const float* startt = (const float*)d_in[4];
  const float* endt   = (const float*)d_in[5];
  float* out = (float*)d_out;

  float* wsL    = (float*)d_ws;               // [16*256]
  float* wsGold = wsL + NCH * 256;            // [16*256]
  int*   wsM    = (int*)(wsGold + NCH * 256); // [16*256]
  float* wsSE   = (float*)(wsM + NCH * 256);  // [256]
  float* wsA    = wsSE + 256;                 // [64*256]
  int*   cnt    = (int*)(wsA + 64 * 256);     // [1] last-block counter

  size_t off = (size_t)((char*)(cnt + 1) - (char*)d_ws);
  off = (off + 255) & ~(size_t)255;
  short* em2 = (short*)((char*)d_ws + off);   // [256 rows x EMROW] bf16 (~33.6 MB)
  const size_t need = off + (size_t)Bn * EMROW * sizeof(short);

  hipMemsetAsync(cnt, 0, sizeof(int), stream);  // ws is poisoned 0xAA pre-launch
  if (ws_size >= need) {
    crf_prep<<<4096, 256, 0, stream>>>(em, em2);
    crf_scan2<<<256, 128, 0, stream>>>(em, tags, mask, trans, startt, endt, em2,
                                       wsL, wsGold, wsM, wsSE, wsA, cnt, out);
  } else {  // fallback: best-known single-kernel (R8)
    crf_scan_fb<<<256, 256, 0, stream>>>(em, tags, mask, trans, startt, endt,
                                         wsL, wsGold, wsM, wsSE, wsA, cnt, out);
  }
}

// Round 13
// 164.594 us; speedup vs baseline: 1.0230x; 1.0189x over previous
//
#include <hip/hip_runtime.h>

#define Bn 256
#define Sn 1024
#define Tn 64
#define NCH 16
#define BURN 64
#define SLAB 4
#define CROW 72             // fb kernel: conv bf16 row stride in shorts
#define MROW 129
#define GSTRIDE 1048576     // em2 group stride in shorts: 1024 t * 16 rows * 64
#define LN2 0.69314718055994531f
#define L7LN2 4.8520302639196169f   // 7*ln2 (lambda = 2^-7 folded into exp)

typedef __attribute__((ext_vector_type(8))) short short8;
typedef __attribute__((ext_vector_type(4))) float f32x4;

__device__ __forceinline__ unsigned short f2bf_rne(float f) {
  unsigned u = __float_as_uint(f);
  u = (u + 0x7fffu + ((u >> 16) & 1u)) >> 16;
  return (unsigned short)u;
}
__device__ __forceinline__ unsigned pk2(float hi, float lo) {
  return __builtin_amdgcn_perm(__float_as_uint(hi), __float_as_uint(lo), 0x07060302);
}
__device__ __forceinline__ unsigned pke(float a, float b) {  // exp+pack 2 bf16
  return (unsigned)f2bf_rne(__expf(a - L7LN2)) |
         ((unsigned)f2bf_rne(__expf(b - L7LN2)) << 16);
}
__device__ __forceinline__ short8 cat4(uint2 a, uint2 b) {
  union { unsigned u[4]; short8 s; } x;
  x.u[0] = a.x; x.u[1] = a.y; x.u[2] = b.x; x.u[3] = b.y;
  return x.s;
}
__device__ __forceinline__ void gl_lds16(const void* src, void* dst) {
  __builtin_amdgcn_global_load_lds(
      (const __attribute__((address_space(1))) void*)src,
      (__attribute__((address_space(3))) void*)dst, 16, 0, 0);
}
__device__ __forceinline__ void gl_lds4(const void* src, void* dst) {
  __builtin_amdgcn_global_load_lds(
      (const __attribute__((address_space(1))) void*)src,
      (__attribute__((address_space(3))) void*)dst, 4, 0, 0);
}

// R13: CONTIGUOUS CONSUMPTION ORDER. R11/R12 pinned the wall: every slow
// variant issues loads of 8-16 SCATTERED 16-128B granules per instruction
// (one per far-apart row) -> per-line latency ~2400cy -> ~1.7 B/cy/CU;
// every fast kernel (prep, m13, m97's GEMM through the SAME gl_lds16 path)
// issues contiguous per-wave transfers. Fix: em2 layout = [g][t][row16][64]
// (t-major within each 16-row group) so a block's whole stream is one
// contiguous 256KB region and each gl_lds16 moves 1KB contiguous
// (lane*16B -- the m97 pattern). Ring layout / swizzle / scan wave /
// vmcnt ladder / pke order all byte-identical to R12 -> absmax 0.
__global__ __launch_bounds__(256) void crf_prep(const float* __restrict__ em,
                                                short* __restrict__ em2) {
  int idx = blockIdx.x * 256 + threadIdx.x;   // 4096*256 == Bn*Sn*4 exactly
  if (idx >= Bn * Sn * 4) return;
  const int cell = idx >> 2;                  // (b,t)
  const int j = idx & 3;                      // q-quadrant
  const int b = cell >> 10;                   // Sn = 1024
  const int t = cell & 1023;
  const float* src = em + (size_t)cell * 64;
  float4 v0 = *(const float4*)(src + 8 * j);
  float4 v1 = *(const float4*)(src + 8 * j + 4);
  float4 v2 = *(const float4*)(src + 32 + 8 * j);
  float4 v3 = *(const float4*)(src + 32 + 8 * j + 4);
  uint4 O1, O2;
  O1.x = pke(v0.x, v0.y); O1.y = pke(v0.z, v0.w);   // states 8j..8j+3
  O1.z = pke(v1.x, v1.y); O1.w = pke(v1.z, v1.w);   // states 8j+4..8j+7
  O2.x = pke(v2.x, v2.y); O2.y = pke(v2.z, v2.w);   // states 32+8j..+3
  O2.z = pke(v3.x, v3.y); O2.w = pke(v3.z, v3.w);   // states 32+8j+4..+7
  // t-major-within-group cell: [g][t][row][64]
  short* dst = em2 + (size_t)(b >> 4) * GSTRIDE + ((size_t)t * 16 + (b & 15)) * 64;
  const int sw = (b & 7) << 3;                // 16B-granule XOR (8 shorts)
  *(uint4*)(dst + ((j * 16) ^ sw)) = O1;      // eu0|eu1 of lane q=j
  *(uint4*)(dst + ((j * 16 + 8) ^ sw)) = O2;  // eu2|eu3 of lane q=j
}

// ======================= kernel 2: bf16 scan ============================
// 256 blocks x 2 waves. wave0: unchanged MFMA scan reading bf16 straight
// from a 4-deep LDS ring. wave1: pure producer -- 8 gl_lds16 of 1KB
// CONTIGUOUS per slab, slab r+3 issued at round r, counted vmcnt (14/6/0).
__global__ __launch_bounds__(128, 1) void crf_scan2(
    const float* __restrict__ em, const int* __restrict__ tags,
    const int* __restrict__ mask, const float* __restrict__ trans,
    const float* __restrict__ startt, const float* __restrict__ endt,
    const short* __restrict__ em2,
    float* __restrict__ wsL, float* __restrict__ wsGold,
    int* __restrict__ wsM, float* __restrict__ wsSE, float* __restrict__ wsA,
    int* __restrict__ cnt, float* __restrict__ out) {
  const int g = blockIdx.x & 15;
  const int c = blockIdx.x >> 4;
  const int Wc = (c == 0) ? 0 : BURN;
  const int Lc = (c == NCH - 1) ? 63 : 64;
  const int TOT = Wc + Lc;
  const int NSLAB = (TOT + SLAB - 1) / SLAB;
  const int t0 = 64 * c + 1;
  const int tstart = t0 - Wc;
  const int tid = threadIdx.x;
  const int wid = tid >> 6;
  const int lane = tid & 63;
  const int m = lane & 15;
  const int q = lane >> 4;
  const int mrow = 8 * (m >> 2) + (m & 3);  // permuted A-row base
  const int swm = (m & 7) << 3;             // matches prep's XOR swizzle

  __shared__ __align__(16) short ring[4][SLAB * 16 * 64];  // 32 KB bf16 em
  __shared__ int maskL[16 * MROW];                         // 8.3 KB
  __shared__ int lastF;
  __shared__ float eend[64];
  __shared__ float rsum[2];

  short8 a00, a01, a10, a11, a20, a21, a30, a31;
  uint2 st0, st1, st2, st3;
  float Slog = 0.f;
  int K = 0, NL = 0;
  const f32x4 zero4 = {0.f, 0.f, 0.f, 0.f};

  // contiguous stream: block (c,g) consumes em2[g][tstart..tstart+TOT)[*][*]
  const short* embase = em2 + (size_t)g * GSTRIDE;
  auto issue_slab = [&](int s) {   // 2*rem x 1KB-contiguous gl_lds16
    if (s >= NSLAB) return;
    short* dstb = ring[s & 3];
    const int rem = min(SLAB, TOT - 4 * s);
    const size_t base = (size_t)(tstart + 4 * s) * 1024;  // 16 rows*64 st.
    const int nI = 2 * rem;                               // 8 full / 6 tail
    for (int k = 0; k < nI; ++k)
      gl_lds16(embase + base + (size_t)k * 512 + (lane << 3),
               dstb + k * 512);
  };

  // ================= prologue =================
  if (wid == 0) {
#define LOADA(tm, kc, dst) { \
    _Pragma("unroll") for (int jj = 0; jj < 8; ++jj) { \
      int kk = kc * 32 + q * 8 + jj; \
      dst[jj] = (short)f2bf_rne(__expf(trans[kk * Tn + (32 * ((tm) >> 1) + 4 * ((tm) & 1) + mrow)])); \
    } }
    LOADA(0, 0, a00) LOADA(0, 1, a01) LOADA(1, 0, a10) LOADA(1, 1, a11)
    LOADA(2, 0, a20) LOADA(2, 1, a21) LOADA(3, 0, a30) LOADA(3, 1, a31)
#undef LOADA
    if (c == 0) {  // exact alpha_0 = exp(startt + em[:,0,:]), permuted slots
#define INIT0(off, ss) { \
      float4 sv = *(const float4*)(startt + (off)); \
      float4 ev = *(const float4*)(em + (size_t)(16 * g + m) * Sn * Tn + (off)); \
      ss.x = (unsigned)f2bf_rne(__expf(sv.x + ev.x)) | \
             ((unsigned)f2bf_rne(__expf(sv.y + ev.y)) << 16); \
      ss.y = (unsigned)f2bf_rne(__expf(sv.z + ev.z)) | \
             ((unsigned)f2bf_rne(__expf(sv.w + ev.w)) << 16); }
      INIT0(8 * q, st0) INIT0(8 * q + 4, st1)
      INIT0(32 + 8 * q, st2) INIT0(36 + 8 * q, st3)
#undef INIT0
    } else {
      st0.x = 0x3F803F80u; st0.y = 0x3F803F80u; st1 = st0; st2 = st0; st3 = st0;
    }
    if (c == NCH - 1 && g == 15) {  // mask repair (wave1 skips this slot)
      int t = tstart + 64 + lane;
      if (t < Sn) maskL[15 * MROW + 64 + lane] = mask[(size_t)255 * Sn + t];
    }
    asm volatile("s_waitcnt vmcnt(0) lgkmcnt(0)" ::: "memory");
  } else {
    // mask staging (gl_lds, oldest in queue)
    for (int mm = 0; mm < 16; ++mm) {
      gl_lds4(mask + (size_t)(16 * g + mm) * Sn + tstart + lane,
              (void*)(maskL + mm * MROW));
      bool special = (c == NCH - 1) && (g == 15) && (mm == 15);  // OOB t=1024
      if (!special)
        gl_lds4(mask + (size_t)(16 * g + mm) * Sn + tstart + 64 + lane,
                (void*)(maskL + mm * MROW + 64));
    }
    // gold partials (plain loads; consumption drains them + older mask)
    {
      const int bm = 16 * g + m;
      const int* tg = tags + (size_t)bm * Sn;
      const int* mkb = mask + (size_t)bm * Sn;
      const float* emb = em + (size_t)bm * Sn * Tn;
      float acc = 0.f;
      int cntg = 0;
      #pragma unroll 4
      for (int i = 0; i < 16; ++i) {
        int t = t0 + q + 4 * i;
        bool ok = t < t0 + Lc;
        int ts = ok ? t : t0;
        int mv = mkb[ts];
        int tp = tg[ts - 1], tc = tg[ts];
        float w = trans[tp * Tn + tc] + emb[(size_t)ts * Tn + tc];
        acc += (ok && mv) ? w : 0.f;
        cntg += ok ? mv : 0;
      }
      acc += __shfl_xor(acc, 16); acc += __shfl_xor(acc, 32);
      cntg += __shfl_xor(cntg, 16); cntg += __shfl_xor(cntg, 32);
      if (q == 0) { wsGold[c * 256 + bm] = acc; wsM[c * 256 + bm] = cntg; }
    }
    asm volatile("s_waitcnt vmcnt(0)" ::: "memory");  // mask+gold done
    issue_slab(0); issue_slab(1); issue_slab(2);
    asm volatile("s_waitcnt vmcnt(16)" ::: "memory"); // slab0 done; 1,2 fly
  }
  __builtin_amdgcn_s_barrier();   // B1: ring[0] + maskL ready
  asm volatile("" ::: "memory");

  // ================= rounds =================
#define UNP(ss, x0, x1, x2, x3) \
  x0 = __uint_as_float(ss.x << 16); x1 = __uint_as_float(ss.x & 0xffff0000u); \
  x2 = __uint_as_float(ss.y << 16); x3 = __uint_as_float(ss.y & 0xffff0000u);

  auto renorm = [&](int ttz) {
    float x00, x01, x02, x03, x10, x11, x12, x13;
    float x20, x21, x22, x23, x30, x31, x32, x33;
    UNP(st0, x00, x01, x02, x03) UNP(st1, x10, x11, x12, x13)
    UNP(st2, x20, x21, x22, x23) UNP(st3, x30, x31, x32, x33)
    float sm = (((x00 + x01) + (x02 + x03)) + ((x10 + x11) + (x12 + x13)))
             + (((x20 + x21) + (x22 + x23)) + ((x30 + x31) + (x32 + x33)));
    sm += __shfl_xor(sm, 16); sm += __shfl_xor(sm, 32);
    if (c != 0 && ttz == BURN) { Slog = __logf(sm); K = 0; NL = 0; }
    int k = 127 - (int)((__float_as_uint(sm) >> 23) & 255u);
    float fk = __uint_as_float((unsigned)(127 + k) << 23);
    x00 *= fk; x01 *= fk; x02 *= fk; x03 *= fk;
    x10 *= fk; x11 *= fk; x12 *= fk; x13 *= fk;
    x20 *= fk; x21 *= fk; x22 *= fk; x23 *= fk;
    x30 *= fk; x31 *= fk; x32 *= fk; x33 *= fk;
    st0.x = pk2(x01, x00); st0.y = pk2(x03, x02);
    st1.x = pk2(x11, x10); st1.y = pk2(x13, x12);
    st2.x = pk2(x21, x20); st2.y = pk2(x23, x22);
    st3.x = pk2(x31, x30); st3.y = pk2(x33, x32);
    K += k;
  };

  auto scan_step = [&](const short* cellb, int tt) {
    uint4 E01 = *(const uint4*)(cellb + ((q * 16) ^ swm));
    uint4 E23 = *(const uint4*)(cellb + ((q * 16 + 8) ^ swm));
    uint2 eu0; eu0.x = E01.x; eu0.y = E01.y;
    uint2 eu1; eu1.x = E01.z; eu1.y = E01.w;
    uint2 eu2; eu2.x = E23.x; eu2.y = E23.y;
    uint2 eu3; eu3.x = E23.z; eu3.y = E23.w;
    int mv = maskL[m * MROW + tt];
    short8 b0 = cat4(st0, st1);
    short8 b1 = cat4(st2, st3);
    f32x4 d0 = __builtin_amdgcn_mfma_f32_16x16x32_bf16(a00, b0, zero4, 0, 0, 0);
    f32x4 d1 = __builtin_amdgcn_mfma_f32_16x16x32_bf16(a10, b0, zero4, 0, 0, 0);
    f32x4 d2 = __builtin_amdgcn_mfma_f32_16x16x32_bf16(a20, b0, zero4, 0, 0, 0);
    f32x4 d3 = __builtin_amdgcn_mfma_f32_16x16x32_bf16(a30, b0, zero4, 0, 0, 0);
    d0 = __builtin_amdgcn_mfma_f32_16x16x32_bf16(a01, b1, d0, 0, 0, 0);
    d1 = __builtin_amdgcn_mfma_f32_16x16x32_bf16(a11, b1, d1, 0, 0, 0);
    d2 = __builtin_amdgcn_mfma_f32_16x16x32_bf16(a21, b1, d2, 0, 0, 0);
    d3 = __builtin_amdgcn_mfma_f32_16x16x32_bf16(a31, b1, d3, 0, 0, 0);
    const bool live = (mv != 0);
#define EPI(dd, eu, ss) { \
    float e0 = __uint_as_float(eu.x << 16); \
    float e1 = __uint_as_float(eu.x & 0xffff0000u); \
    float e2 = __uint_as_float(eu.y << 16); \
    float e3 = __uint_as_float(eu.y & 0xffff0000u); \
    unsigned nx = pk2(dd[1] * e1, dd[0] * e0); \
    unsigned ny = pk2(dd[3] * e3, dd[2] * e2); \
    ss.x = live ? nx : ss.x; \
    ss.y = live ? ny : ss.y; }
    EPI(d0, eu0, st0) EPI(d1, eu1, st1) EPI(d2, eu2, st2) EPI(d3, eu3, st3)
#undef EPI
    NL += (live && tt >= Wc) ? 1 : 0;
  };

  const int RT = (TOT - 4) >> 2;
  for (int r = 0; r < NSLAB; ++r) {
    if (wid == 0) {
      if ((r & 1) == 0) renorm(4 * r);
      const short* rb = ring[r & 3];
      if (r < RT) {
        #pragma unroll
        for (int u = 0; u < SLAB; ++u)
          scan_step(rb + (u * 16 + m) * 64, 4 * r + u);
      } else {
        #pragma unroll
        for (int u = 0; u < SLAB; ++u)
          if (4 * r + u < TOT)
            scan_step(rb + (u * 16 + m) * 64, 4 * r + u);
      }
    } else {
      issue_slab(r + 3);   // into ring[(r+3)&3]; ring[r&3] read this round
      // in-order vmcnt: drain slab r+1; keep r+2,r+3 in flight.
      if (r + 3 < NSLAB)      asm volatile("s_waitcnt vmcnt(14)" ::: "memory");
      else if (r + 2 < NSLAB) asm volatile("s_waitcnt vmcnt(6)" ::: "memory");
      else                    asm volatile("s_waitcnt vmcnt(0)" ::: "memory");
    }
    __builtin_amdgcn_s_barrier();
    asm volatile("" ::: "memory");
  }

  // ================= per-chunk outputs =================
  if (wid == 0) {
    float x00, x01, x02, x03, x10, x11, x12, x13;
    float x20, x21, x22, x23, x30, x31, x32, x33;
    UNP(st0, x00, x01, x02, x03) UNP(st1, x10, x11, x12, x13)
    UNP(st2, x20, x21, x22, x23) UNP(st3, x30, x31, x32, x33)
    float sm = (((x00 + x01) + (x02 + x03)) + ((x10 + x11) + (x12 + x13)))
             + (((x20 + x21) + (x22 + x23)) + ((x30 + x31) + (x32 + x33)));
    sm += __shfl_xor(sm, 16); sm += __shfl_xor(sm, 32);
    const int bm = 16 * g + m;
    float L = __logf(sm) - Slog + LN2 * (float)(7 * NL - K);
    if (q == 0) wsL[c * 256 + bm] = L;
    if (c == NCH - 1) {
      if (q == 0) wsSE[bm] = __logf(sm);
      wsA[(8 * q + 0) * 256 + bm] = x00;  wsA[(8 * q + 1) * 256 + bm] = x01;
      wsA[(8 * q + 2) * 256 + bm] = x02;  wsA[(8 * q + 3) * 256 + bm] = x03;
      wsA[(8 * q + 4) * 256 + bm] = x10;  wsA[(8 * q + 5) * 256 + bm] = x11;
      wsA[(8 * q + 6) * 256 + bm] = x12;  wsA[(8 * q + 7) * 256 + bm] = x13;
      wsA[(32 + 8 * q + 0) * 256 + bm] = x20; wsA[(32 + 8 * q + 1) * 256 + bm] = x21;
      wsA[(32 + 8 * q + 2) * 256 + bm] = x22; wsA[(32 + 8 * q + 3) * 256 + bm] = x23;
      wsA[(36 + 8 * q + 0) * 256 + bm] = x30; wsA[(36 + 8 * q + 1) * 256 + bm] = x31;
      wsA[(36 + 8 * q + 2) * 256 + bm] = x32; wsA[(36 + 8 * q + 3) * 256 + bm] = x33;
    }
  }
#undef UNP

  // ================= fused finale (last block) =================
  __threadfence();
  __syncthreads();
  if (tid == 0) lastF = (atomicAdd(cnt, 1) == 255) ? 1 : 0;
  __syncthreads();
  if (lastF) {
    __threadfence();
    if (tid < 64) eend[tid] = __expf(endt[tid]);
    __syncthreads();
    float vsum = 0.f;
    for (int bb = tid; bb < Bn; bb += 128) {
      float sumL = 0.f, gold = 0.f;
      int msum = 0;
      #pragma unroll
      for (int cc = 0; cc < NCH; ++cc) {
        sumL += wsL[cc * 256 + bb];
        gold += wsGold[cc * 256 + bb];
        msum += wsM[cc * 256 + bb];
      }
      msum += mask[(size_t)bb * Sn];
      float se = 0.f;
      for (int jj = 0; jj < Tn; ++jj) se += wsA[jj * 256 + bb] * eend[jj];
      float logZ = sumL + __logf(se) - wsSE[bb];
      int tg0 = tags[(size_t)bb * Sn];
      int lastTag = tags[(size_t)bb * Sn + (msum - 1)];
      gold += startt[tg0] + em[(size_t)bb * Sn * Tn + tg0] + endt[lastTag];
      vsum += logZ - gold;
    }
    #pragma unroll
    for (int o = 32; o > 0; o >>= 1) vsum += __shfl_xor(vsum, o, 64);
    if (lane == 0) rsum[wid] = vsum;
    __syncthreads();
    if (tid == 0) out[0] = (rsum[0] + rsum[1]) * (1.0f / Bn);
  }
}

// =============== fallback: R8 kernel verbatim (ws too small) ===============
__global__ __launch_bounds__(256, 1) void crf_scan_fb(
    const float* __restrict__ em, const int* __restrict__ tags,
    const int* __restrict__ mask, const float* __restrict__ trans,
    const float* __restrict__ startt, const float* __restrict__ endt,
    float* __restrict__ wsL, float* __restrict__ wsGold,
    int* __restrict__ wsM, float* __restrict__ wsSE, float* __restrict__ wsA,
    int* __restrict__ cnt, float* __restrict__ out) {
  const int g = blockIdx.x & 15;
  const int c = blockIdx.x >> 4;
  const int Wc = (c == 0) ? 0 : BURN;
  const int Lc = (c == NCH - 1) ? 63 : 64;
  const int TOT = Wc + Lc;
  const int NSLAB = (TOT + SLAB - 1) / SLAB;
  const int t0 = 64 * c + 1;
  const int tstart = t0 - Wc;
  const int tid = threadIdx.x;
  const int wid = tid >> 6;
  const int lane = tid & 63;
  const int m = lane & 15;
  const int q = lane >> 4;
  const int mrow = 8 * (m >> 2) + (m & 3);

  __shared__ __align__(16) short convS[2][SLAB * 16 * CROW];
  __shared__ int maskL[16 * MROW];
  __shared__ int lastF;
  __shared__ float eend[64];
  __shared__ float rsum[4];

  short8 a00, a01, a10, a11, a20, a21, a30, a31;
  uint2 st0, st1, st2, st3;
  float Slog = 0.f;
  int K = 0, NL = 0;
  const f32x4 zero4 = {0.f, 0.f, 0.f, 0.f};

  const int mm_ = lane & 15, seg_ = lane >> 4;
  const int base_ = (seg_ >> 1) * 32 + (seg_ & 1) * 8;
  const size_t rowoff = (size_t)(16 * g + mm_) * Sn;
  const int ua = (wid == 1) ? 0 : 2;
  float4 A0, A1, A2, A3, A4, A5, A6, A7;
  float4 B0, B1, B2, B3, B4, B5, B6, B7;
  float4 C0, C1, C2, C3, C4, C5, C6, C7;
  float4 D0, D1, D2, D3, D4, D5, D6, D7;

#define LOADS(P, s) do { if ((s) < NSLAB) { \
    int ta_ = tstart + 4 * (s) + ua;  int tb_ = ta_ + 1; \
    ta_ = min(ta_, Sn - 1);  tb_ = min(tb_, Sn - 1); \
    const float* pa_ = em + (rowoff + ta_) * 64 + seg_ * 16; \
    const float* pb_ = em + (rowoff + tb_) * 64 + seg_ * 16; \
    P##0 = *(const float4*)(pa_);      P##1 = *(const float4*)(pa_ + 4); \
    P##2 = *(const float4*)(pa_ + 8);  P##3 = *(const float4*)(pa_ + 12); \
    P##4 = *(const float4*)(pb_);      P##5 = *(const float4*)(pb_ + 4); \
    P##6 = *(const float4*)(pb_ + 8);  P##7 = *(const float4*)(pb_ + 12); } } while (0)

#define CONVW(P, s) do { if ((s) < NSLAB) { \
    short* cb_ = convS[(s) & 1]; \
    uint4 o0_, o1_; \
    o0_.x = pke((P##0).x, (P##0).y); o0_.y = pke((P##0).z, (P##0).w); \
    o1_.x = pke((P##1).x, (P##1).y); o1_.y = pke((P##1).z, (P##1).w); \
    o0_.z = pke((P##2).x, (P##2).y); o0_.w = pke((P##2).z, (P##2).w); \
    o1_.z = pke((P##3).x, (P##3).y); o1_.w = pke((P##3).z, (P##3).w); \
    short* cw_ = cb_ + (ua * 16 + mm_) * CROW + base_; \
    *(uint4*)(cw_) = o0_;  *(uint4*)(cw_ + 16) = o1_; \
    o0_.x = pke((P##4).x, (P##4).y); o0_.y = pke((P##4).z, (P##4).w); \
    o1_.x = pke((P##5).x, (P##5).y); o1_.y = pke((P##5).z, (P##5).w); \
    o0_.z = pke((P##6).x, (P##6).y); o0_.w = pke((P##6).z, (P##6).w); \
    o1_.z = pke((P##7).x, (P##7).y); o1_.w = pke((P##7).z, (P##7).w); \
    cw_ = cb_ + ((ua + 1) * 16 + mm_) * CROW + base_; \
    *(uint4*)(cw_) = o0_;  *(uint4*)(cw_ + 16) = o1_; } } while (0)

  if (wid == 0) {
#define LOADA(tm, kc, dst) { \
    _Pragma("unroll") for (int jj = 0; jj < 8; ++jj) { \
      int kk = kc * 32 + q * 8 + jj; \
      dst[jj] = (short)f2bf_rne(__expf(trans[kk * Tn + (32 * ((tm) >> 1) + 4 * ((tm) & 1) + mrow)])); \
    } }
    LOADA(0, 0, a00) LOADA(0, 1, a01) LOADA(1, 0, a10) LOADA(1, 1, a11)
    LOADA(2, 0, a20) LOADA(2, 1, a21) LOADA(3, 0, a30) LOADA(3, 1, a31)
#undef LOADA
    if (c == 0) {
#define INIT0(off, ss) { \
      float4 sv = *(const float4*)(startt + (off)); \
      float4 ev = *(const float4*)(em + (size_t)(16 * g + m) * Sn * Tn + (off)); \
      ss.x = (unsigned)f2bf_rne(__expf(sv.x + ev.x)) | \
             ((unsigned)f2bf_rne(__expf(sv.y + ev.y)) << 16); \
      ss.y = (unsigned)f2bf_rne(__expf(sv.z + ev.z)) | \
             ((unsigned)f2bf_rne(__expf(sv.w + ev.w)) << 16); }
      INIT0(8 * q, st0) INIT0(8 * q + 4, st1)
      INIT0(32 + 8 * q, st2) INIT0(36 + 8 * q, st3)
#undef INIT0
    } else {
      st0.x = 0x3F803F80u; st0.y = 0x3F803F80u; st1 = st0; st2 = st0; st3 = st0;
    }
  } else if (wid == 3) {
    for (int mm = 0; mm < 16; ++mm) {
      gl_lds4(mask + (size_t)(16 * g + mm) * Sn + tstart + lane,
              (void*)(maskL + mm * MROW));
      bool special = (c == NCH - 1) && (g == 15) && (mm == 15);
      if (!special)
        gl_lds4(mask + (size_t)(16 * g + mm) * Sn + tstart + 64 + lane,
                (void*)(maskL + mm * MROW + 64));
    }
    {
      const int bm = 16 * g + m;
      const int* tg = tags + (size_t)bm * Sn;
      const int* mkb = mask + (size_t)bm * Sn;
      const float* emb = em + (size_t)bm * Sn * Tn;
      float acc = 0.f;
      int cntg = 0;
      #pragma unroll 4
      for (int i = 0; i < 16; ++i) {
        int t = t0 + q + 4 * i;
        bool ok = t < t0 + Lc;
        int ts = ok ? t : t0;
        int mv = mkb[ts];
        int tp = tg[ts - 1], tc = tg[ts];
        float w = trans[tp * Tn + tc] + emb[(size_t)ts * Tn + tc];
        acc += (ok && mv) ? w : 0.f;
        cntg += ok ? mv : 0;
      }
      acc += __shfl_xor(acc, 16); acc += __shfl_xor(acc, 32);
      cntg += __shfl_xor(cntg, 16); cntg += __shfl_xor(cntg, 32);
      if (q == 0) { wsGold[c * 256 + bm] = acc; wsM[c * 256 + bm] = cntg; }
    }
    if (c == NCH - 1 && g == 15) {
      int t = tstart + 64 + lane;
      if (t < Sn) maskL[15 * MROW + 64 + lane] = mask[(size_t)255 * Sn + t];
    }
    asm volatile("s_waitcnt vmcnt(0) lgkmcnt(0)" ::: "memory");
  } else {
    LOADS(A, 0);
    LOADS(B, 1);
    LOADS(C, 2);
    LOADS(D, 3);
    CONVW(A, 0);
    asm volatile("s_waitcnt lgkmcnt(0)" ::: "memory");
  }
  __builtin_amdgcn_s_barrier();
  asm volatile("" ::: "memory");

#define UNP(ss, x0, x1, x2, x3) \
  x0 = __uint_as_float(ss.x << 16); x1 = __uint_as_float(ss.x & 0xffff0000u); \
  x2 = __uint_as_float(ss.y << 16); x3 = __uint_as_float(ss.y & 0xffff0000u);

  auto renorm = [&](int ttz) {
    float x00, x01, x02, x03, x10, x11, x12, x13;
    float x20, x21, x22, x23, x30, x31, x32, x33;
    UNP(st0, x00, x01, x02, x03) UNP(st1, x10, x11, x12, x13)
    UNP(st2, x20, x21, x22, x23) UNP(st3, x30, x31, x32, x33)
    float sm = (((x00 + x01) + (x02 + x03)) + ((x10 + x11) + (x12 + x13)))
             + (((x20 + x21) + (x22 + x23)) + ((x30 + x31) + (x32 + x33)));
    sm += __shfl_xor(sm, 16); sm += __shfl_xor(sm, 32);
    if (c != 0 && ttz == BURN) { Slog = __logf(sm); K = 0; NL = 0; }
    int k = 127 - (int)((__float_as_uint(sm) >> 23) & 255u);
    float fk = __uint_as_float((unsigned)(127 + k) << 23);
    x00 *= fk; x01 *= fk; x02 *= fk; x03 *= fk;
    x10 *= fk; x11 *= fk; x12 *= fk; x13 *= fk;
    x20 *= fk; x21 *= fk; x22 *= fk; x23 *= fk;
    x30 *= fk; x31 *= fk; x32 *= fk; x33 *= fk;
    st0.x = pk2(x01, x00); st0.y = pk2(x03, x02);
    st1.x = pk2(x11, x10); st1.y = pk2(x13, x12);
    st2.x = pk2(x21, x20); st2.y = pk2(x23, x22);
    st3.x = pk2(x31, x30); st3.y = pk2(x33, x32);
    K += k;
  };

  auto scan_step = [&](const short* ep, int tt) {
    uint2 eu0 = *(const uint2*)(ep + 0 + 4 * q);
    uint2 eu1 = *(const uint2*)(ep + 16 + 4 * q);
    uint2 eu2 = *(const uint2*)(ep + 32 + 4 * q);
    uint2 eu3 = *(const uint2*)(ep + 48 + 4 * q);
    int mv = maskL[m * MROW + tt];
    short8 b0 = cat4(st0, st1);
    short8 b1 = cat4(st2, st3);
    f32x4 d0 = __builtin_amdgcn_mfma_f32_16x16x32_bf16(a00, b0, zero4, 0, 0, 0);
    f32x4 d1 = __builtin_amdgcn_mfma_f32_16x16x32_bf16(a10, b0, zero4, 0, 0, 0);
    f32x4 d2 = __builtin_amdgcn_mfma_f32_16x16x32_bf16(a20, b0, zero4, 0, 0, 0);
    f32x4 d3 = __builtin_amdgcn_mfma_f32_16x16x32_bf16(a30, b0, zero4, 0, 0, 0);
    d0 = __builtin_amdgcn_mfma_f32_16x16x32_bf16(a01, b1, d0, 0, 0, 0);
    d1 = __builtin_amdgcn_mfma_f32_16x16x32_bf16(a11, b1, d1, 0, 0, 0);
    d2 = __builtin_amdgcn_mfma_f32_16x16x32_bf16(a21, b1, d2, 0, 0, 0);
    d3 = __builtin_amdgcn_mfma_f32_16x16x32_bf16(a31, b1, d3, 0, 0, 0);
    const bool live = (mv != 0);
#define EPI(dd, eu, ss) { \
    float e0 = __uint_as_float(eu.x << 16); \
    float e1 = __uint_as_float(eu.x & 0xffff0000u); \
    float e2 = __uint_as_float(eu.y << 16); \
    float e3 = __uint_as_float(eu.y & 0xffff0000u); \
    unsigned nx = pk2(dd[1] * e1, dd[0] * e0); \
    unsigned ny = pk2(dd[3] * e3, dd[2] * e2); \
    ss.x = live ? nx : ss.x; \
    ss.y = live ? ny : ss.y; }
    EPI(d0, eu0, st0) EPI(d1, eu1, st1) EPI(d2, eu2, st2) EPI(d3, eu3, st3)
#undef EPI
    NL += (live && tt >= Wc) ? 1 : 0;
  };

  const int RT = (TOT - 4) >> 2;
  for (int r = 0; r < NSLAB; ++r) {
    if (wid == 0) {
      if ((r & 1) == 0) renorm(4 * r);
      const short* cbase = convS[r & 1];
      if (r < RT) {
        #pragma unroll
        for (int u = 0; u < SLAB; ++u)
          scan_step(cbase + (u * 16 + m) * CROW, 4 * r + u);
      } else {
        #pragma unroll
        for (int u = 0; u < SLAB; ++u)
          if (4 * r + u < TOT)
            scan_step(cbase + (u * 16 + m) * CROW, 4 * r + u);
      }
    } else if (wid == 1 || wid == 2) {
      switch (r & 3) {
        case 0: LOADS(A, r + 4); CONVW(B, r + 1); break;
        case 1: LOADS(B, r + 4); CONVW(C, r + 1); break;
        case 2: LOADS(C, r + 4); CONVW(D, r + 1); break;
        default: LOADS(D, r + 4); CONVW(A, r + 1); break;
      }
      asm volatile("s_waitcnt lgkmcnt(0)" ::: "memory");
    }
    __builtin_amdgcn_s_barrier();
    asm volatile("" ::: "memory");
  }
#undef LOADS
#undef CONVW

  if (wid == 0) {
    float x00, x01, x02, x03, x10, x11, x12, x13;
    float x20, x21, x22, x23, x30, x31, x32, x33;
    UNP(st0, x00, x01, x02, x03) UNP(st1, x10, x11, x12, x13)
    UNP(st2, x20, x21, x22, x23) UNP(st3, x30, x31, x32, x33)
    float sm = (((x00 + x01) + (x02 + x03)) + ((x10 + x11) + (x12 + x13)))
             + (((x20 + x21) + (x22 + x23)) + ((x30 + x31) + (x32 + x33)));
    sm += __shfl_xor(sm, 16); sm += __shfl_xor(sm, 32);
    const int bm = 16 * g + m;
    float L = __logf(sm) - Slog + LN2 * (float)(7 * NL - K);
    if (q == 0) wsL[c * 256 + bm] = L;
    if (c == NCH - 1) {
      if (q == 0) wsSE[bm] = __logf(sm);
      wsA[(8 * q + 0) * 256 + bm] = x00;  wsA[(8 * q + 1) * 256 + bm] = x01;
      wsA[(8 * q + 2) * 256 + bm] = x02;  wsA[(8 * q + 3) * 256 + bm] = x03;
      wsA[(8 * q + 4) * 256 + bm] = x10;  wsA[(8 * q + 5) * 256 + bm] = x11;
      wsA[(8 * q + 6) * 256 + bm] = x12;  wsA[(8 * q + 7) * 256 + bm] = x13;
      wsA[(32 + 8 * q + 0) * 256 + bm] = x20; wsA[(32 + 8 * q + 1) * 256 + bm] = x21;
      wsA[(32 + 8 * q + 2) * 256 + bm] = x22; wsA[(32 + 8 * q + 3) * 256 + bm] = x23;
      wsA[(36 + 8 * q + 0) * 256 + bm] = x30; wsA[(36 + 8 * q + 1) * 256 + bm] = x31;
      wsA[(36 + 8 * q + 2) * 256 + bm] = x32; wsA[(36 + 8 * q + 3) * 256 + bm] = x33;
    }
  }
#undef UNP

  __threadfence();
  __syncthreads();
  if (tid == 0) lastF = (atomicAdd(cnt, 1) == 255) ? 1 : 0;
  __syncthreads();
  if (lastF) {
    __threadfence();
    if (tid < 64) eend[tid] = __expf(endt[tid]);
    __syncthreads();
    float vsum = 0.f;
    for (int bb = tid; bb < Bn; bb += 256) {
      float sumL = 0.f, gold = 0.f;
      int msum = 0;
      #pragma unroll
      for (int cc = 0; cc < NCH; ++cc) {
        sumL += wsL[cc * 256 + bb];
        gold += wsGold[cc * 256 + bb];
        msum += wsM[cc * 256 + bb];
      }
      msum += mask[(size_t)bb * Sn];
      float se = 0.f;
      for (int jj = 0; jj < Tn; ++jj) se += wsA[jj * 256 + bb] * eend[jj];
      float logZ = sumL + __logf(se) - wsSE[bb];
      int tg0 = tags[(size_t)bb * Sn];
      int lastTag = tags[(size_t)bb * Sn + (msum - 1)];
      gold += startt[tg0] + em[(size_t)bb * Sn * Tn + tg0] + endt[lastTag];
      vsum += logZ - gold;
    }
    #pragma unroll
    for (int o = 32; o > 0; o >>= 1) vsum += __shfl_xor(vsum, o, 64);
    if (lane == 0) rsum[wid] = vsum;
    __syncthreads();
    if (tid == 0) out[0] = (rsum[0] + rsum[1] + rsum[2] + rsum[3]) * (1.0f / Bn);
  }
}

extern "C" void kernel_launch(void* const* d_in, const int* in_sizes, int n_in,
                              void* d_out, int out_size, void* d_ws, size_t ws_size,
                              hipStream_t stream) {
  const float* em     = (const float*)d_in[0];
  const int*   tags   = (const int*)d_in[1];
  const int*   mask   = (const int*)d_in[2];
  const float* trans  = (const float*)d_in[3];
  const float* startt = (const float*)d_in[4];
  const float* endt   = (const float*)d_in[5];
  float* out = (float*)d_out;

  float* wsL    = (float*)d_ws;               // [16*256]
  float* wsGold = wsL + NCH * 256;            // [16*256]
  int*   wsM    = (int*)(wsGold + NCH * 256); // [16*256]
  float* wsSE   = (float*)(wsM + NCH * 256);  // [256]
  float* wsA    = wsSE + 256;                 // [64*256]
  int*   cnt    = (int*)(wsA + 64 * 256);     // [1] last-block counter

  size_t off = (size_t)((char*)(cnt + 1) - (char*)d_ws);
  off = (off + 255) & ~(size_t)255;
  short* em2 = (short*)((char*)d_ws + off);   // [16 groups x GSTRIDE] bf16 (32 MB)
  const size_t need = off + (size_t)16 * GSTRIDE * sizeof(short);

  hipMemsetAsync(cnt, 0, sizeof(int), stream);  // ws is poisoned 0xAA pre-launch
  if (ws_size >= need) {
    crf_prep<<<4096, 256, 0, stream>>>(em, em2);
    crf_scan2<<<256, 128, 0, stream>>>(em, tags, mask, trans, startt, endt, em2,
                                       wsL, wsGold, wsM, wsSE, wsA, cnt, out);
  } else {  // fallback: best-known single-kernel (R8)
    crf_scan_fb<<<256, 256, 0, stream>>>(em, tags, mask, trans, startt, endt,
                                         wsL, wsGold, wsM, wsSE, wsA, cnt, out);
  }
}